// Round 1
// baseline (2109.341 us; speedup 1.0000x reference)
//
#include <hip/hip_runtime.h>
#include <math.h>

#define BB 128
#define TT 64
#define DD 64
#define HH 128
#define NHH 4
#define RR 16          // batch rows per GRU block
#define GRU_THREADS 384
#define K3H 384        // 3*H

// ---------------- transpose Whh [D,3H,H] -> WT [D,H,3H] (k fastest) --------
__global__ void transpose_whh(const float* __restrict__ Whh, float* __restrict__ WT) {
    int idx = blockIdx.x * 256 + threadIdx.x;      // over D*H*3H = 3145728
    int k = idx % K3H;
    int rem = idx / K3H;
    int j = rem % HH;
    int d = rem / HH;
    WT[idx] = Whh[(d * K3H + k) * HH + j];
}

// ---------------- per-feature GRU --------------------------------------
// grid: dim3(64 /*d*/, 8 /*batch split*/), block: 384 threads (1 per k col)
__global__ __launch_bounds__(GRU_THREADS) void gru_kernel(
    const float* __restrict__ x, const int* __restrict__ mask,
    const float* __restrict__ Wih, const float* __restrict__ bih,
    const float* __restrict__ bhh, const float* __restrict__ WT,
    float* __restrict__ emb)
{
    int d  = blockIdx.x;
    int b0 = blockIdx.y * RR;
    int tid = threadIdx.x;

    __shared__ float h_s[RR][HH];        // 8 KB
    __shared__ float gh_s[RR][K3H];      // 24 KB
    __shared__ float wih_s[K3H], bih_s[K3H], bhh_s[K3H];
    __shared__ float xt_s[RR];
    __shared__ int   tstar_s[RR];

    if (tid < K3H) {
        wih_s[tid] = Wih[d * K3H + tid];
        bih_s[tid] = bih[d * K3H + tid];
        bhh_s[tid] = bhh[d * K3H + tid];
    }
    if (tid < RR) {
        int b = b0 + tid;
        int len = 0;
        for (int t = 0; t < TT; ++t) len += mask[b * TT + t];
        int ts = len - 1;
        if (ts < 0) ts = 0;
        if (ts > TT - 1) ts = TT - 1;
        tstar_s[tid] = ts;
    }
    for (int i = tid; i < RR * HH; i += GRU_THREADS) ((float*)h_s)[i] = 0.f;
    __syncthreads();

    const float* Wd = WT + (size_t)d * HH * K3H;   // [j][k]
    const int k = tid;                              // 0..383
    const float* wp = Wd + k;
    const float bk = bhh_s[k];

    for (int t = 0; t < TT; ++t) {
        if (tid < RR) xt_s[tid] = x[((b0 + tid) * TT + t) * DD + d];

        // gh[r][k] = bhh[k] + sum_j h[r][j] * WT[j][k]
        float acc[RR];
#pragma unroll
        for (int r = 0; r < RR; ++r) acc[r] = bk;
#pragma unroll 2
        for (int j = 0; j < HH; j += 4) {
            float w0 = wp[(j + 0) * K3H];
            float w1 = wp[(j + 1) * K3H];
            float w2 = wp[(j + 2) * K3H];
            float w3 = wp[(j + 3) * K3H];
#pragma unroll
            for (int r = 0; r < RR; ++r) {
                float4 h4 = *(const float4*)&h_s[r][j];
                acc[r] = fmaf(h4.x, w0, acc[r]);
                acc[r] = fmaf(h4.y, w1, acc[r]);
                acc[r] = fmaf(h4.z, w2, acc[r]);
                acc[r] = fmaf(h4.w, w3, acc[r]);
            }
        }
#pragma unroll
        for (int r = 0; r < RR; ++r) gh_s[r][k] = acc[r];
        __syncthreads();

        // gates: r,z,n and state update
        for (int idx = tid; idx < RR * HH; idx += GRU_THREADS) {
            int row = idx >> 7, hh = idx & (HH - 1);
            float xt  = xt_s[row];
            float gr  = fmaf(xt, wih_s[hh],          bih_s[hh])          + gh_s[row][hh];
            float gz  = fmaf(xt, wih_s[HH + hh],     bih_s[HH + hh])     + gh_s[row][HH + hh];
            float gnx = fmaf(xt, wih_s[2 * HH + hh], bih_s[2 * HH + hh]);
            float ghn = gh_s[row][2 * HH + hh];
            float rg = 1.f / (1.f + __expf(-gr));
            float zg = 1.f / (1.f + __expf(-gz));
            float ng = tanhf(fmaf(rg, ghn, gnx));
            float hprev = h_s[row][hh];
            float hn = (1.f - zg) * ng + zg * hprev;
            h_s[row][hh] = hn;
            if (t == tstar_s[row])
                emb[((b0 + row) * DD + d) * HH + hh] = hn;
        }
        __syncthreads();
    }
}

// ---------------- generic small matmul: C[M,N] = act(A[M,K] @ W[K,N] + b) ---
// block 256 threads: 16 rows x 128 cols tile; grid.x = M/16, grid.y = N/128
template <int KDIM, int NDIM, int RELU>
__global__ __launch_bounds__(256) void mm_kernel(
    const float* __restrict__ A, const float* __restrict__ W,
    const float* __restrict__ bias, float* __restrict__ C)
{
    __shared__ float A_s[16][KDIM];
    int tid = threadIdx.x;
    int row0 = blockIdx.x * 16;
    int col = blockIdx.y * 128 + (tid & 127);
    int rg = tid >> 7;   // 0 or 1
    for (int i = tid; i < 16 * KDIM; i += 256) {
        int r = i / KDIM, kk = i % KDIM;
        A_s[r][kk] = A[(size_t)(row0 + r) * KDIM + kk];
    }
    __syncthreads();
    float acc[8];
#pragma unroll
    for (int r = 0; r < 8; ++r) acc[r] = 0.f;
    for (int kk = 0; kk < KDIM; ++kk) {
        float w = W[kk * NDIM + col];
#pragma unroll
        for (int r = 0; r < 8; ++r)
            acc[r] = fmaf(A_s[rg * 8 + r][kk], w, acc[r]);
    }
    float bv = bias[col];
#pragma unroll
    for (int r = 0; r < 8; ++r) {
        float v = acc[r] + bv;
        if (RELU) v = v > 0.f ? v : 0.f;
        C[(size_t)(row0 + rg * 8 + r) * NDIM + col] = v;
    }
}

// ---------------- MHA core: per (b, head) -------------------------------
__global__ __launch_bounds__(64) void attn_kernel(
    const float* __restrict__ qb, const float* __restrict__ kb,
    const float* __restrict__ vb, float* __restrict__ ob)
{
    int b = blockIdx.x, hd = blockIdx.y;
    int i = threadIdx.x;  // query token 0..63
    __shared__ float k_s[DD][32];
    __shared__ float v_s[DD][32];
    __shared__ float s_s[DD][DD + 1];
    for (int idx = i; idx < DD * 32; idx += 64) {
        int dd = idx >> 5, m = idx & 31;
        k_s[dd][m] = kb[((size_t)b * DD + dd) * HH + hd * 32 + m];
        v_s[dd][m] = vb[((size_t)b * DD + dd) * HH + hd * 32 + m];
    }
    float q[32];
#pragma unroll
    for (int m = 0; m < 32; ++m) q[m] = qb[((size_t)b * DD + i) * HH + hd * 32 + m];
    __syncthreads();
    const float scale = 0.17677669529663687f;  // 1/sqrt(32)
    float mx = -1e30f;
    for (int j = 0; j < DD; ++j) {
        float s = 0.f;
#pragma unroll
        for (int m = 0; m < 32; ++m) s = fmaf(q[m], k_s[j][m], s);
        s *= scale;
        s_s[i][j] = s;
        mx = fmaxf(mx, s);
    }
    float sum = 0.f;
    for (int j = 0; j < DD; ++j) {
        float p = __expf(s_s[i][j] - mx);
        s_s[i][j] = p;
        sum += p;
    }
    float inv = 1.f / sum;
    float o[32];
#pragma unroll
    for (int m = 0; m < 32; ++m) o[m] = 0.f;
    for (int j = 0; j < DD; ++j) {
        float p = s_s[i][j] * inv;
#pragma unroll
        for (int m = 0; m < 32; ++m) o[m] = fmaf(p, v_s[j][m], o[m]);
    }
#pragma unroll
    for (int m = 0; m < 32; ++m)
        ob[((size_t)b * DD + i) * HH + hd * 32 + m] = o[m];
}

// ---------------- residual add + LayerNorm (row = H=128) -----------------
__global__ __launch_bounds__(64) void addln_kernel(
    const float* __restrict__ xr, const float* __restrict__ y,
    const float* __restrict__ g, const float* __restrict__ be,
    float* __restrict__ out)
{
    int row = blockIdx.x;
    int t = threadIdx.x;
    float v0 = xr[(size_t)row * HH + t]      + y[(size_t)row * HH + t];
    float v1 = xr[(size_t)row * HH + t + 64] + y[(size_t)row * HH + t + 64];
    float s = v0 + v1;
    for (int o = 32; o; o >>= 1) s += __shfl_xor(s, o);
    float mean = s * (1.f / 128.f);
    float d0 = v0 - mean, d1 = v1 - mean;
    float vs = d0 * d0 + d1 * d1;
    for (int o = 32; o; o >>= 1) vs += __shfl_xor(vs, o);
    float rs = rsqrtf(vs * (1.f / 128.f) + 1e-5f);
    out[(size_t)row * HH + t]      = d0 * rs * g[t]      + be[t];
    out[(size_t)row * HH + t + 64] = d1 * rs * g[t + 64] + be[t + 64];
}

// ---------------- final QKV attention, one block per batch element --------
__global__ __launch_bounds__(128) void final_kernel(
    const float* __restrict__ h2,
    const float* __restrict__ Fq, const float* __restrict__ fbq,
    const float* __restrict__ Fk, const float* __restrict__ fbk,
    const float* __restrict__ Fv, const float* __restrict__ fbv,
    const float* __restrict__ Fout, const float* __restrict__ fbout,
    float* __restrict__ out)
{
    int b = blockIdx.x;
    int t = threadIdx.x;  // 0..127
    __shared__ float h2_s[DD][HH];
    __shared__ float fk_s[DD][HH];
    __shared__ float fv_s[DD][HH];
    __shared__ float fq_s[HH];
    __shared__ float fo_s[HH];
    __shared__ float e_s[DD];
    for (int idx = t; idx < DD * HH; idx += 128)
        ((float*)h2_s)[idx] = h2[(size_t)b * DD * HH + idx];
    fo_s[t] = Fout[t];
    __syncthreads();
    {
        float a = fbq[t];
        for (int m = 0; m < HH; ++m) a = fmaf(h2_s[DD - 1][m], Fq[m * HH + t], a);
        fq_s[t] = a;
    }
    for (int dd = 0; dd < DD; ++dd) {
        float ak = fbk[t], av = fbv[t];
        for (int m = 0; m < HH; ++m) {
            float hm = h2_s[dd][m];
            ak = fmaf(hm, Fk[m * HH + t], ak);
            av = fmaf(hm, Fv[m * HH + t], av);
        }
        fk_s[dd][t] = ak;
        fv_s[dd][t] = av;
    }
    __syncthreads();
    if (t < DD) {
        float e = fbout[0];
        for (int m = 0; m < HH; ++m)
            e = fmaf(tanhf(fq_s[m] + fk_s[t][m]), fo_s[m], e);
        e_s[t] = e;
    }
    __syncthreads();
    if (t < 64) {   // wave 0: softmax over D=64
        float e = e_s[t];
        float mx = e;
        for (int o = 32; o; o >>= 1) mx = fmaxf(mx, __shfl_xor(mx, o));
        float p = __expf(e - mx);
        float s = p;
        for (int o = 32; o; o >>= 1) s += __shfl_xor(s, o);
        e_s[t] = p / s;
    }
    __syncthreads();
    float acc = 0.f;
    for (int dd = 0; dd < DD; ++dd) acc = fmaf(e_s[dd], fv_s[dd][t], acc);
    out[(size_t)b * HH + t] = acc;
}

// ---------------- launch ---------------------------------------------------
extern "C" void kernel_launch(void* const* d_in, const int* in_sizes, int n_in,
                              void* d_out, int out_size, void* d_ws, size_t ws_size,
                              hipStream_t stream)
{
    const float* x    = (const float*)d_in[0];
    const int*   mask = (const int*)d_in[1];
    const float* Wih  = (const float*)d_in[2];
    const float* Whh  = (const float*)d_in[3];
    const float* bih  = (const float*)d_in[4];
    const float* bhh  = (const float*)d_in[5];
    const float* Wq = (const float*)d_in[6];   const float* bq = (const float*)d_in[7];
    const float* Wk = (const float*)d_in[8];   const float* bk = (const float*)d_in[9];
    const float* Wv = (const float*)d_in[10];  const float* bv = (const float*)d_in[11];
    const float* Wo = (const float*)d_in[12];  const float* bo = (const float*)d_in[13];
    const float* W1 = (const float*)d_in[14];  const float* b1 = (const float*)d_in[15];
    const float* W2 = (const float*)d_in[16];  const float* b2 = (const float*)d_in[17];
    const float* g1 = (const float*)d_in[18];  const float* be1 = (const float*)d_in[19];
    const float* g2 = (const float*)d_in[20];  const float* be2 = (const float*)d_in[21];
    const float* Fq = (const float*)d_in[22];  const float* fbq = (const float*)d_in[23];
    const float* Fk = (const float*)d_in[24];  const float* fbk = (const float*)d_in[25];
    const float* Fv = (const float*)d_in[26];  const float* fbv = (const float*)d_in[27];
    const float* Fout = (const float*)d_in[28]; const float* fbout = (const float*)d_in[29];
    float* out = (float*)d_out;
    float* ws  = (float*)d_ws;

    float* WT  = ws;                 // 3145728
    float* emb = ws + 3145728;       // 1048576
    float* qb  = ws + 4194304;
    float* kb  = ws + 5242880;
    float* vb  = ws + 6291456;
    float* ob  = ws + 7340032;
    float* h1  = ws + 8388608;
    float* tmp = ws + 9437184;
    float* a1  = ws + 10485760;      // 2097152
    float* h2  = ws + 12582912;      // end 13631488 floats (~54.5 MB)

    transpose_whh<<<12288, 256, 0, stream>>>(Whh, WT);
    gru_kernel<<<dim3(DD, BB / RR), GRU_THREADS, 0, stream>>>(x, mask, Wih, bih, bhh, WT, emb);
    mm_kernel<128, 128, 0><<<dim3(512, 1), 256, 0, stream>>>(emb, Wq, bq, qb);
    mm_kernel<128, 128, 0><<<dim3(512, 1), 256, 0, stream>>>(emb, Wk, bk, kb);
    mm_kernel<128, 128, 0><<<dim3(512, 1), 256, 0, stream>>>(emb, Wv, bv, vb);
    attn_kernel<<<dim3(BB, NHH), 64, 0, stream>>>(qb, kb, vb, ob);
    mm_kernel<128, 128, 0><<<dim3(512, 1), 256, 0, stream>>>(ob, Wo, bo, tmp);
    addln_kernel<<<BB * DD, 64, 0, stream>>>(emb, tmp, g1, be1, h1);
    mm_kernel<128, 256, 1><<<dim3(512, 2), 256, 0, stream>>>(h1, W1, b1, a1);
    mm_kernel<256, 128, 0><<<dim3(512, 1), 256, 0, stream>>>(a1, W2, b2, tmp);
    addln_kernel<<<BB * DD, 64, 0, stream>>>(h1, tmp, g2, be2, h2);
    final_kernel<<<BB, 128, 0, stream>>>(h2, Fq, fbq, Fk, fbk, Fv, fbv, Fout, fbout, out);
}

// Round 2
// 761.355 us; speedup vs baseline: 2.7705x; 2.7705x over previous
//
#include <hip/hip_runtime.h>
#include <math.h>

#define BB 128
#define TT 64
#define DD 64
#define HH 128
#define NHH 4
#define K3H 384        // 3*H

typedef __attribute__((ext_vector_type(8))) short short8_t;   // 8 bf16
typedef __attribute__((ext_vector_type(4))) float float4_t;

__device__ __forceinline__ unsigned short f2bf(float f) {
    unsigned int u = __float_as_uint(f);
    u += 0x7fffu + ((u >> 16) & 1u);      // RNE
    return (unsigned short)(u >> 16);
}

// ---------------- per-feature GRU via bf16 MFMA ---------------------------
// grid: dim3(64 /*d*/, 8 /*batch split of 16*/), block: 256 threads (4 waves)
// wave w owns hh columns [32w, 32w+32) for all 3 gates (6 MFMA n-tiles).
__global__ __launch_bounds__(256) void gru_mfma_kernel(
    const float* __restrict__ x, const int* __restrict__ mask,
    const float* __restrict__ Wih, const float* __restrict__ Whh,
    const float* __restrict__ bih, const float* __restrict__ bhh,
    float* __restrict__ emb)
{
    const int d  = blockIdx.x;
    const int b0 = blockIdx.y * 16;
    const int tid = threadIdx.x;
    const int w = tid >> 6;          // wave 0..3
    const int l = tid & 63;          // lane
    const int m = l & 15;            // A row / C col index
    const int q = l >> 4;            // quad 0..3

    __shared__ __align__(16) unsigned short hbuf[2][16][136]; // +8 pad, 8704 B
    __shared__ float xs[16][TT];                              // 4 KB
    __shared__ int tstar_s[16];

    // ---- stage x[b0..b0+15][t][d] ----
    for (int idx = tid; idx < 16 * TT; idx += 256) {
        int row = idx >> 6, t = idx & 63;
        xs[row][t] = x[((size_t)(b0 + row) * TT + t) * DD + d];
    }
    if (tid < 16) {
        int b = b0 + tid, len = 0;
        for (int t = 0; t < TT; ++t) len += mask[b * TT + t];
        int ts = len - 1;
        if (ts < 0) ts = 0;
        if (ts > TT - 1) ts = TT - 1;
        tstar_s[tid] = ts;
    }
    for (int idx = tid; idx < 16 * 136; idx += 256)
        ((unsigned short*)hbuf)[idx] = 0;   // zero buffer 0

    // ---- load W fragments (B operand), once ----
    // tile tl: gate g = tl>>1, n0 = g*128 + 32*w + (tl&1)*16
    short8_t Bf[6][4];
#pragma unroll
    for (int tl = 0; tl < 6; ++tl) {
        int n0 = (tl >> 1) * HH + 32 * w + (tl & 1) * 16;
        int kcol = n0 + m;                         // gate-col in 3H
        const float* wrow = Whh + ((size_t)d * K3H + kcol) * HH;
#pragma unroll
        for (int kc = 0; kc < 4; ++kc) {
            int j0 = kc * 32 + q * 8;
            float4 w0 = *(const float4*)(wrow + j0);
            float4 w1 = *(const float4*)(wrow + j0 + 4);
            short8_t f;
            f[0] = (short)f2bf(w0.x); f[1] = (short)f2bf(w0.y);
            f[2] = (short)f2bf(w0.z); f[3] = (short)f2bf(w0.w);
            f[4] = (short)f2bf(w1.x); f[5] = (short)f2bf(w1.y);
            f[6] = (short)f2bf(w1.z); f[7] = (short)f2bf(w1.w);
            Bf[tl][kc] = f;
        }
    }

    // ---- per-lane gate constants (hh = 32w + m and +16) ----
    int hh[2] = {32 * w + m, 32 * w + 16 + m};
    float wih_r[2], wih_z[2], wih_n[2], bsum_r[2], bsum_z[2], bih_n[2], bhh_n[2];
#pragma unroll
    for (int tt = 0; tt < 2; ++tt) {
        int h0 = hh[tt];
        wih_r[tt] = Wih[d * K3H + h0];
        wih_z[tt] = Wih[d * K3H + HH + h0];
        wih_n[tt] = Wih[d * K3H + 2 * HH + h0];
        bsum_r[tt] = bih[d * K3H + h0] + bhh[d * K3H + h0];
        bsum_z[tt] = bih[d * K3H + HH + h0] + bhh[d * K3H + HH + h0];
        bih_n[tt] = bih[d * K3H + 2 * HH + h0];
        bhh_n[tt] = bhh[d * K3H + 2 * HH + h0];
    }

    float hprev[8];
#pragma unroll
    for (int i = 0; i < 8; ++i) hprev[i] = 0.f;

    __syncthreads();

    for (int t = 0; t < TT; ++t) {
        const unsigned short* hb = &hbuf[t & 1][0][0];
        unsigned short* hbn = &hbuf[(t & 1) ^ 1][0][0];

        // A fragments: lane holds h[m][kc*32 + q*8 + 0..7]
        short8_t A[4];
#pragma unroll
        for (int kc = 0; kc < 4; ++kc)
            A[kc] = *(const short8_t*)(hb + m * 136 + kc * 32 + q * 8);

        float4_t acc[6];
#pragma unroll
        for (int tl = 0; tl < 6; ++tl) {
            float4_t a = {0.f, 0.f, 0.f, 0.f};
#pragma unroll
            for (int kc = 0; kc < 4; ++kc)
                a = __builtin_amdgcn_mfma_f32_16x16x32_bf16(A[kc], Bf[tl][kc], a, 0, 0, 0);
            acc[tl] = a;
        }

        // gates: lane owns rows q*4+reg, cols hh[tt]; h carried fp32 in regs
#pragma unroll
        for (int tt = 0; tt < 2; ++tt) {
#pragma unroll
            for (int reg = 0; reg < 4; ++reg) {
                int row = q * 4 + reg;
                float xv = xs[row][t];
                float gr = acc[0 + tt][reg] + fmaf(xv, wih_r[tt], bsum_r[tt]);
                float gz = acc[2 + tt][reg] + fmaf(xv, wih_z[tt], bsum_z[tt]);
                float rg = 1.f / (1.f + __expf(-gr));
                float zg = 1.f / (1.f + __expf(-gz));
                float gnh = acc[4 + tt][reg] + bhh_n[tt];
                float gn = fmaf(rg, gnh, fmaf(xv, wih_n[tt], bih_n[tt]));
                float ng = 1.f - 2.f / (__expf(2.f * gn) + 1.f);
                float hp = hprev[tt * 4 + reg];
                float hn = fmaf(zg, hp - ng, ng);
                hprev[tt * 4 + reg] = hn;
                hbn[row * 136 + hh[tt]] = f2bf(hn);
                if (t == tstar_s[row])
                    emb[(((size_t)(b0 + row)) * DD + d) * HH + hh[tt]] = hn;
            }
        }
        __syncthreads();
    }
}

// ---------------- generic small matmul: C[M,N] = act(A[M,K] @ W[K,N] + b) ---
template <int KDIM, int NDIM, int RELU>
__global__ __launch_bounds__(256) void mm_kernel(
    const float* __restrict__ A, const float* __restrict__ W,
    const float* __restrict__ bias, float* __restrict__ C)
{
    __shared__ float A_s[16][KDIM];
    int tid = threadIdx.x;
    int row0 = blockIdx.x * 16;
    int col = blockIdx.y * 128 + (tid & 127);
    int rg = tid >> 7;   // 0 or 1
    for (int i = tid; i < 16 * KDIM; i += 256) {
        int r = i / KDIM, kk = i % KDIM;
        A_s[r][kk] = A[(size_t)(row0 + r) * KDIM + kk];
    }
    __syncthreads();
    float acc[8];
#pragma unroll
    for (int r = 0; r < 8; ++r) acc[r] = 0.f;
    for (int kk = 0; kk < KDIM; ++kk) {
        float w = W[kk * NDIM + col];
#pragma unroll
        for (int r = 0; r < 8; ++r)
            acc[r] = fmaf(A_s[rg * 8 + r][kk], w, acc[r]);
    }
    float bv = bias[col];
#pragma unroll
    for (int r = 0; r < 8; ++r) {
        float v = acc[r] + bv;
        if (RELU) v = v > 0.f ? v : 0.f;
        C[(size_t)(row0 + rg * 8 + r) * NDIM + col] = v;
    }
}

// ---------------- MHA core: per (b, head) -------------------------------
__global__ __launch_bounds__(64) void attn_kernel(
    const float* __restrict__ qb, const float* __restrict__ kb,
    const float* __restrict__ vb, float* __restrict__ ob)
{
    int b = blockIdx.x, hd = blockIdx.y;
    int i = threadIdx.x;  // query token 0..63
    __shared__ float k_s[DD][32];
    __shared__ float v_s[DD][32];
    __shared__ float s_s[DD][DD + 1];
    for (int idx = i; idx < DD * 32; idx += 64) {
        int dd = idx >> 5, mm = idx & 31;
        k_s[dd][mm] = kb[((size_t)b * DD + dd) * HH + hd * 32 + mm];
        v_s[dd][mm] = vb[((size_t)b * DD + dd) * HH + hd * 32 + mm];
    }
    float qv[32];
#pragma unroll
    for (int mm = 0; mm < 32; ++mm) qv[mm] = qb[((size_t)b * DD + i) * HH + hd * 32 + mm];
    __syncthreads();
    const float scale = 0.17677669529663687f;  // 1/sqrt(32)
    float mx = -1e30f;
    for (int j = 0; j < DD; ++j) {
        float s = 0.f;
#pragma unroll
        for (int mm = 0; mm < 32; ++mm) s = fmaf(qv[mm], k_s[j][mm], s);
        s *= scale;
        s_s[i][j] = s;
        mx = fmaxf(mx, s);
    }
    float sum = 0.f;
    for (int j = 0; j < DD; ++j) {
        float p = __expf(s_s[i][j] - mx);
        s_s[i][j] = p;
        sum += p;
    }
    float inv = 1.f / sum;
    float o[32];
#pragma unroll
    for (int mm = 0; mm < 32; ++mm) o[mm] = 0.f;
    for (int j = 0; j < DD; ++j) {
        float p = s_s[i][j] * inv;
#pragma unroll
        for (int mm = 0; mm < 32; ++mm) o[mm] = fmaf(p, v_s[j][mm], o[mm]);
    }
#pragma unroll
    for (int mm = 0; mm < 32; ++mm)
        ob[((size_t)b * DD + i) * HH + hd * 32 + mm] = o[mm];
}

// ---------------- residual add + LayerNorm (row = H=128) -----------------
__global__ __launch_bounds__(64) void addln_kernel(
    const float* __restrict__ xr, const float* __restrict__ y,
    const float* __restrict__ g, const float* __restrict__ be,
    float* __restrict__ out)
{
    int row = blockIdx.x;
    int t = threadIdx.x;
    float v0 = xr[(size_t)row * HH + t]      + y[(size_t)row * HH + t];
    float v1 = xr[(size_t)row * HH + t + 64] + y[(size_t)row * HH + t + 64];
    float s = v0 + v1;
    for (int o = 32; o; o >>= 1) s += __shfl_xor(s, o);
    float mean = s * (1.f / 128.f);
    float d0 = v0 - mean, d1 = v1 - mean;
    float vs = d0 * d0 + d1 * d1;
    for (int o = 32; o; o >>= 1) vs += __shfl_xor(vs, o);
    float rs = rsqrtf(vs * (1.f / 128.f) + 1e-5f);
    out[(size_t)row * HH + t]      = d0 * rs * g[t]      + be[t];
    out[(size_t)row * HH + t + 64] = d1 * rs * g[t + 64] + be[t + 64];
}

// ---------------- final QKV attention, one block per batch element --------
__global__ __launch_bounds__(128) void final_kernel(
    const float* __restrict__ h2,
    const float* __restrict__ Fq, const float* __restrict__ fbq,
    const float* __restrict__ Fk, const float* __restrict__ fbk,
    const float* __restrict__ Fv, const float* __restrict__ fbv,
    const float* __restrict__ Fout, const float* __restrict__ fbout,
    float* __restrict__ out)
{
    int b = blockIdx.x;
    int t = threadIdx.x;  // 0..127
    __shared__ float h2_s[DD][HH];
    __shared__ float fk_s[DD][HH];
    __shared__ float fv_s[DD][HH];
    __shared__ float fq_s[HH];
    __shared__ float fo_s[HH];
    __shared__ float e_s[DD];
    for (int idx = t; idx < DD * HH; idx += 128)
        ((float*)h2_s)[idx] = h2[(size_t)b * DD * HH + idx];
    fo_s[t] = Fout[t];
    __syncthreads();
    {
        float a = fbq[t];
        for (int mm = 0; mm < HH; ++mm) a = fmaf(h2_s[DD - 1][mm], Fq[mm * HH + t], a);
        fq_s[t] = a;
    }
    for (int dd = 0; dd < DD; ++dd) {
        float ak = fbk[t], av = fbv[t];
        for (int mm = 0; mm < HH; ++mm) {
            float hm = h2_s[dd][mm];
            ak = fmaf(hm, Fk[mm * HH + t], ak);
            av = fmaf(hm, Fv[mm * HH + t], av);
        }
        fk_s[dd][t] = ak;
        fv_s[dd][t] = av;
    }
    __syncthreads();
    if (t < DD) {
        float e = fbout[0];
        for (int mm = 0; mm < HH; ++mm)
            e = fmaf(tanhf(fq_s[mm] + fk_s[t][mm]), fo_s[mm], e);
        e_s[t] = e;
    }
    __syncthreads();
    if (t < 64) {   // wave 0: softmax over D=64
        float e = e_s[t];
        float mx = e;
        for (int o = 32; o; o >>= 1) mx = fmaxf(mx, __shfl_xor(mx, o));
        float p = __expf(e - mx);
        float s = p;
        for (int o = 32; o; o >>= 1) s += __shfl_xor(s, o);
        e_s[t] = p / s;
    }
    __syncthreads();
    float acc = 0.f;
    for (int dd = 0; dd < DD; ++dd) acc = fmaf(e_s[dd], fv_s[dd][t], acc);
    out[(size_t)b * HH + t] = acc;
}

// ---------------- launch ---------------------------------------------------
extern "C" void kernel_launch(void* const* d_in, const int* in_sizes, int n_in,
                              void* d_out, int out_size, void* d_ws, size_t ws_size,
                              hipStream_t stream)
{
    const float* x    = (const float*)d_in[0];
    const int*   mask = (const int*)d_in[1];
    const float* Wih  = (const float*)d_in[2];
    const float* Whh  = (const float*)d_in[3];
    const float* bih  = (const float*)d_in[4];
    const float* bhh  = (const float*)d_in[5];
    const float* Wq = (const float*)d_in[6];   const float* bq = (const float*)d_in[7];
    const float* Wk = (const float*)d_in[8];   const float* bk = (const float*)d_in[9];
    const float* Wv = (const float*)d_in[10];  const float* bv = (const float*)d_in[11];
    const float* Wo = (const float*)d_in[12];  const float* bo = (const float*)d_in[13];
    const float* W1 = (const float*)d_in[14];  const float* b1 = (const float*)d_in[15];
    const float* W2 = (const float*)d_in[16];  const float* b2 = (const float*)d_in[17];
    const float* g1 = (const float*)d_in[18];  const float* be1 = (const float*)d_in[19];
    const float* g2 = (const float*)d_in[20];  const float* be2 = (const float*)d_in[21];
    const float* Fq = (const float*)d_in[22];  const float* fbq = (const float*)d_in[23];
    const float* Fk = (const float*)d_in[24];  const float* fbk = (const float*)d_in[25];
    const float* Fv = (const float*)d_in[26];  const float* fbv = (const float*)d_in[27];
    const float* Fout = (const float*)d_in[28]; const float* fbout = (const float*)d_in[29];
    float* out = (float*)d_out;
    float* ws  = (float*)d_ws;

    float* emb = ws;                 // 1048576
    float* qb  = ws + 1048576;
    float* kb  = ws + 2097152;
    float* vb  = ws + 3145728;
    float* ob  = ws + 4194304;
    float* h1  = ws + 5242880;
    float* tmp = ws + 6291456;
    float* a1  = ws + 7340032;       // 2097152
    float* h2  = ws + 9437184;       // end 10485760 floats (~42 MB)

    gru_mfma_kernel<<<dim3(DD, BB / 16), 256, 0, stream>>>(x, mask, Wih, Whh, bih, bhh, emb);
    mm_kernel<128, 128, 0><<<dim3(512, 1), 256, 0, stream>>>(emb, Wq, bq, qb);
    mm_kernel<128, 128, 0><<<dim3(512, 1), 256, 0, stream>>>(emb, Wk, bk, kb);
    mm_kernel<128, 128, 0><<<dim3(512, 1), 256, 0, stream>>>(emb, Wv, bv, vb);
    attn_kernel<<<dim3(BB, NHH), 64, 0, stream>>>(qb, kb, vb, ob);
    mm_kernel<128, 128, 0><<<dim3(512, 1), 256, 0, stream>>>(ob, Wo, bo, tmp);
    addln_kernel<<<BB * DD, 64, 0, stream>>>(emb, tmp, g1, be1, h1);
    mm_kernel<128, 256, 1><<<dim3(512, 2), 256, 0, stream>>>(h1, W1, b1, a1);
    mm_kernel<256, 128, 0><<<dim3(512, 1), 256, 0, stream>>>(a1, W2, b2, tmp);
    addln_kernel<<<BB * DD, 64, 0, stream>>>(h1, tmp, g2, be2, h2);
    final_kernel<<<BB, 128, 0, stream>>>(h2, Fq, fbq, Fk, fbk, Fv, fbv, Fout, fbout, out);
}

// Round 3
// 486.237 us; speedup vs baseline: 4.3381x; 1.5658x over previous
//
#include <hip/hip_runtime.h>
#include <math.h>

#define BB 128
#define TT 64
#define DD 64
#define HH 128
#define NHH 4
#define K3H 384        // 3*H

typedef __attribute__((ext_vector_type(8))) short short8_t;   // 8 bf16
typedef __attribute__((ext_vector_type(4))) float float4_t;

__device__ __forceinline__ unsigned short f2bf(float f) {
    unsigned int u = __float_as_uint(f);
    u += 0x7fffu + ((u >> 16) & 1u);      // RNE
    return (unsigned short)(u >> 16);
}

// ---------------- per-feature GRU via bf16 MFMA ---------------------------
// grid: dim3(64 /*d*/, 8 /*batch split of 16*/), block: 256 threads (4 waves)
__global__ __launch_bounds__(256) void gru_mfma_kernel(
    const float* __restrict__ x, const int* __restrict__ mask,
    const float* __restrict__ Wih, const float* __restrict__ Whh,
    const float* __restrict__ bih, const float* __restrict__ bhh,
    float* __restrict__ emb)
{
    const int d  = blockIdx.x;
    const int b0 = blockIdx.y * 16;
    const int tid = threadIdx.x;
    const int w = tid >> 6;          // wave 0..3
    const int l = tid & 63;          // lane
    const int m = l & 15;            // A row / C col index
    const int q = l >> 4;            // quad 0..3

    __shared__ __align__(16) unsigned short hbuf[2][16][136]; // +8 pad
    __shared__ float xs[16][TT];
    __shared__ int tstar_s[16];

    for (int idx = tid; idx < 16 * TT; idx += 256) {
        int row = idx >> 6, t = idx & 63;
        xs[row][t] = x[((size_t)(b0 + row) * TT + t) * DD + d];
    }
    if (tid < 16) {
        int b = b0 + tid, len = 0;
        for (int t = 0; t < TT; ++t) len += mask[b * TT + t];
        int ts = len - 1;
        if (ts < 0) ts = 0;
        if (ts > TT - 1) ts = TT - 1;
        tstar_s[tid] = ts;
    }
    for (int idx = tid; idx < 16 * 136; idx += 256)
        ((unsigned short*)hbuf)[idx] = 0;

    short8_t Bf[6][4];
#pragma unroll
    for (int tl = 0; tl < 6; ++tl) {
        int n0 = (tl >> 1) * HH + 32 * w + (tl & 1) * 16;
        int kcol = n0 + m;
        const float* wrow = Whh + ((size_t)d * K3H + kcol) * HH;
#pragma unroll
        for (int kc = 0; kc < 4; ++kc) {
            int j0 = kc * 32 + q * 8;
            float4 w0 = *(const float4*)(wrow + j0);
            float4 w1 = *(const float4*)(wrow + j0 + 4);
            short8_t f;
            f[0] = (short)f2bf(w0.x); f[1] = (short)f2bf(w0.y);
            f[2] = (short)f2bf(w0.z); f[3] = (short)f2bf(w0.w);
            f[4] = (short)f2bf(w1.x); f[5] = (short)f2bf(w1.y);
            f[6] = (short)f2bf(w1.z); f[7] = (short)f2bf(w1.w);
            Bf[tl][kc] = f;
        }
    }

    int hh[2] = {32 * w + m, 32 * w + 16 + m};
    float wih_r[2], wih_z[2], wih_n[2], bsum_r[2], bsum_z[2], bih_n[2], bhh_n[2];
#pragma unroll
    for (int tt = 0; tt < 2; ++tt) {
        int h0 = hh[tt];
        wih_r[tt] = Wih[d * K3H + h0];
        wih_z[tt] = Wih[d * K3H + HH + h0];
        wih_n[tt] = Wih[d * K3H + 2 * HH + h0];
        bsum_r[tt] = bih[d * K3H + h0] + bhh[d * K3H + h0];
        bsum_z[tt] = bih[d * K3H + HH + h0] + bhh[d * K3H + HH + h0];
        bih_n[tt] = bih[d * K3H + 2 * HH + h0];
        bhh_n[tt] = bhh[d * K3H + 2 * HH + h0];
    }

    float hprev[8];
#pragma unroll
    for (int i = 0; i < 8; ++i) hprev[i] = 0.f;

    __syncthreads();

    for (int t = 0; t < TT; ++t) {
        const unsigned short* hb = &hbuf[t & 1][0][0];
        unsigned short* hbn = &hbuf[(t & 1) ^ 1][0][0];

        short8_t A[4];
#pragma unroll
        for (int kc = 0; kc < 4; ++kc)
            A[kc] = *(const short8_t*)(hb + m * 136 + kc * 32 + q * 8);

        float4_t acc[6];
#pragma unroll
        for (int tl = 0; tl < 6; ++tl) {
            float4_t a = {0.f, 0.f, 0.f, 0.f};
#pragma unroll
            for (int kc = 0; kc < 4; ++kc)
                a = __builtin_amdgcn_mfma_f32_16x16x32_bf16(A[kc], Bf[tl][kc], a, 0, 0, 0);
            acc[tl] = a;
        }

#pragma unroll
        for (int tt = 0; tt < 2; ++tt) {
#pragma unroll
            for (int reg = 0; reg < 4; ++reg) {
                int row = q * 4 + reg;
                float xv = xs[row][t];
                float gr = acc[0 + tt][reg] + fmaf(xv, wih_r[tt], bsum_r[tt]);
                float gz = acc[2 + tt][reg] + fmaf(xv, wih_z[tt], bsum_z[tt]);
                float rg = 1.f / (1.f + __expf(-gr));
                float zg = 1.f / (1.f + __expf(-gz));
                float gnh = acc[4 + tt][reg] + bhh_n[tt];
                float gn = fmaf(rg, gnh, fmaf(xv, wih_n[tt], bih_n[tt]));
                float ng = 1.f - 2.f / (__expf(2.f * gn) + 1.f);
                float hp = hprev[tt * 4 + reg];
                float hn = fmaf(zg, hp - ng, ng);
                hprev[tt * 4 + reg] = hn;
                hbn[row * 136 + hh[tt]] = f2bf(hn);
                if (t == tstar_s[row])
                    emb[(((size_t)(b0 + row)) * DD + d) * HH + hh[tt]] = hn;
            }
        }
        __syncthreads();
    }
}

// ---------------- plain matmul: C = act(A @ W + b) ------------------------
template <int KDIM, int NDIM, int RELU>
__global__ __launch_bounds__(256) void mm_kernel(
    const float* __restrict__ A, const float* __restrict__ W,
    const float* __restrict__ bias, float* __restrict__ C)
{
    __shared__ float A_s[16][KDIM];
    int tid = threadIdx.x;
    int row0 = blockIdx.x * 16;
    int col = blockIdx.y * 128 + (tid & 127);
    int rg = tid >> 7;
    for (int i = tid; i < 16 * KDIM; i += 256) {
        int r = i / KDIM, kk = i % KDIM;
        A_s[r][kk] = A[(size_t)(row0 + r) * KDIM + kk];
    }
    __syncthreads();
    float acc[8];
#pragma unroll
    for (int r = 0; r < 8; ++r) acc[r] = 0.f;
    for (int kk = 0; kk < KDIM; ++kk) {
        float w = W[kk * NDIM + col];
#pragma unroll
        for (int r = 0; r < 8; ++r)
            acc[r] = fmaf(A_s[rg * 8 + r][kk], w, acc[r]);
    }
    float bv = bias[col];
#pragma unroll
    for (int r = 0; r < 8; ++r) {
        float v = acc[r] + bv;
        if (RELU) v = v > 0.f ? v : 0.f;
        C[(size_t)(row0 + rg * 8 + r) * NDIM + col] = v;
    }
}

// ---------------- fused triple matmul q,k,v = emb @ {Wq,Wk,Wv} + b --------
__global__ __launch_bounds__(256) void qkv3_kernel(
    const float* __restrict__ A,
    const float* __restrict__ Wq, const float* __restrict__ bq,
    const float* __restrict__ Wk, const float* __restrict__ bk,
    const float* __restrict__ Wv, const float* __restrict__ bv,
    float* __restrict__ qb, float* __restrict__ kb, float* __restrict__ vb)
{
    __shared__ float A_s[16][HH];
    int tid = threadIdx.x;
    int row0 = blockIdx.x * 16;
    int col = tid & 127, rg = tid >> 7;
    for (int i = tid; i < 16 * HH; i += 256) {
        int r = i >> 7, kk = i & 127;
        A_s[r][kk] = A[(size_t)(row0 + r) * HH + kk];
    }
    __syncthreads();
    float aq[8], ak[8], av[8];
#pragma unroll
    for (int r = 0; r < 8; ++r) { aq[r] = 0.f; ak[r] = 0.f; av[r] = 0.f; }
    for (int kk = 0; kk < HH; ++kk) {
        float wq = Wq[kk * HH + col];
        float wk = Wk[kk * HH + col];
        float wv = Wv[kk * HH + col];
#pragma unroll
        for (int r = 0; r < 8; ++r) {
            float a = A_s[rg * 8 + r][kk];
            aq[r] = fmaf(a, wq, aq[r]);
            ak[r] = fmaf(a, wk, ak[r]);
            av[r] = fmaf(a, wv, av[r]);
        }
    }
    float bqv = bq[col], bkv = bk[col], bvv = bv[col];
#pragma unroll
    for (int r = 0; r < 8; ++r) {
        size_t o = (size_t)(row0 + rg * 8 + r) * HH + col;
        qb[o] = aq[r] + bqv;
        kb[o] = ak[r] + bkv;
        vb[o] = av[r] + bvv;
    }
}

// ---------------- fused dual matmul fk,fv = h2 @ {Fk,Fv} + b --------------
__global__ __launch_bounds__(256) void kv2_kernel(
    const float* __restrict__ A,
    const float* __restrict__ Fk, const float* __restrict__ fbk,
    const float* __restrict__ Fv, const float* __restrict__ fbv,
    float* __restrict__ fkb, float* __restrict__ fvb)
{
    __shared__ float A_s[16][HH];
    int tid = threadIdx.x;
    int row0 = blockIdx.x * 16;
    int col = tid & 127, rg = tid >> 7;
    for (int i = tid; i < 16 * HH; i += 256) {
        int r = i >> 7, kk = i & 127;
        A_s[r][kk] = A[(size_t)(row0 + r) * HH + kk];
    }
    __syncthreads();
    float ak[8], av[8];
#pragma unroll
    for (int r = 0; r < 8; ++r) { ak[r] = 0.f; av[r] = 0.f; }
    for (int kk = 0; kk < HH; ++kk) {
        float wk = Fk[kk * HH + col];
        float wv = Fv[kk * HH + col];
#pragma unroll
        for (int r = 0; r < 8; ++r) {
            float a = A_s[rg * 8 + r][kk];
            ak[r] = fmaf(a, wk, ak[r]);
            av[r] = fmaf(a, wv, av[r]);
        }
    }
    float bkv = fbk[col], bvv = fbv[col];
#pragma unroll
    for (int r = 0; r < 8; ++r) {
        size_t o = (size_t)(row0 + rg * 8 + r) * HH + col;
        fkb[o] = ak[r] + bkv;
        fvb[o] = av[r] + bvv;
    }
}

// ---------------- matmul + residual + LayerNorm epilogue (N=128) ----------
template <int KDIM>
__global__ __launch_bounds__(256) void mm_ln_kernel(
    const float* __restrict__ A, const float* __restrict__ W,
    const float* __restrict__ bias, const float* __restrict__ res,
    const float* __restrict__ g, const float* __restrict__ be,
    float* __restrict__ C)
{
    __shared__ float A_s[16][KDIM];
    __shared__ float v_s[16][HH + 1];
    __shared__ float mv_s[16][2];
    int tid = threadIdx.x;
    int row0 = blockIdx.x * 16;
    int col = tid & 127, rg = tid >> 7;
    for (int i = tid; i < 16 * KDIM; i += 256) {
        int r = i / KDIM, kk = i % KDIM;
        A_s[r][kk] = A[(size_t)(row0 + r) * KDIM + kk];
    }
    __syncthreads();
    float acc[8];
#pragma unroll
    for (int r = 0; r < 8; ++r) acc[r] = 0.f;
    for (int kk = 0; kk < KDIM; ++kk) {
        float w = W[kk * HH + col];
#pragma unroll
        for (int r = 0; r < 8; ++r)
            acc[r] = fmaf(A_s[rg * 8 + r][kk], w, acc[r]);
    }
    float bv = bias[col];
#pragma unroll
    for (int r = 0; r < 8; ++r) {
        int row = rg * 8 + r;
        v_s[row][col] = acc[r] + bv + res[(size_t)(row0 + row) * HH + col];
    }
    __syncthreads();
    int r2 = tid >> 4, j = tid & 15;
    float s = 0.f;
#pragma unroll
    for (int c = 0; c < 8; ++c) s += v_s[r2][j * 8 + c];
    s += __shfl_xor(s, 1); s += __shfl_xor(s, 2);
    s += __shfl_xor(s, 4); s += __shfl_xor(s, 8);
    float mean = s * (1.f / 128.f);
    float vs = 0.f;
#pragma unroll
    for (int c = 0; c < 8; ++c) {
        float dv = v_s[r2][j * 8 + c] - mean;
        vs += dv * dv;
    }
    vs += __shfl_xor(vs, 1); vs += __shfl_xor(vs, 2);
    vs += __shfl_xor(vs, 4); vs += __shfl_xor(vs, 8);
    if (j == 0) {
        mv_s[r2][0] = mean;
        mv_s[r2][1] = rsqrtf(vs * (1.f / 128.f) + 1e-5f);
    }
    __syncthreads();
    float gv = g[col], bev = be[col];
#pragma unroll
    for (int r = 0; r < 8; ++r) {
        int row = rg * 8 + r;
        float mn = mv_s[row][0], rs = mv_s[row][1];
        C[(size_t)(row0 + row) * HH + col] = (v_s[row][col] - mn) * rs * gv + bev;
    }
}

// ---------------- MHA core: per (b, head) -------------------------------
__global__ __launch_bounds__(64) void attn_kernel(
    const float* __restrict__ qb, const float* __restrict__ kb,
    const float* __restrict__ vb, float* __restrict__ ob)
{
    int b = blockIdx.x, hd = blockIdx.y;
    int i = threadIdx.x;
    __shared__ float k_s[DD][32];
    __shared__ float v_s[DD][32];
    __shared__ float s_s[DD][DD + 1];
    for (int idx = i; idx < DD * 32; idx += 64) {
        int dd = idx >> 5, mm = idx & 31;
        k_s[dd][mm] = kb[((size_t)b * DD + dd) * HH + hd * 32 + mm];
        v_s[dd][mm] = vb[((size_t)b * DD + dd) * HH + hd * 32 + mm];
    }
    float qv[32];
#pragma unroll
    for (int mm = 0; mm < 32; ++mm) qv[mm] = qb[((size_t)b * DD + i) * HH + hd * 32 + mm];
    __syncthreads();
    const float scale = 0.17677669529663687f;
    float mx = -1e30f;
    for (int j = 0; j < DD; ++j) {
        float s = 0.f;
#pragma unroll
        for (int mm = 0; mm < 32; ++mm) s = fmaf(qv[mm], k_s[j][mm], s);
        s *= scale;
        s_s[i][j] = s;
        mx = fmaxf(mx, s);
    }
    float sum = 0.f;
    for (int j = 0; j < DD; ++j) {
        float p = __expf(s_s[i][j] - mx);
        s_s[i][j] = p;
        sum += p;
    }
    float inv = 1.f / sum;
    float o[32];
#pragma unroll
    for (int mm = 0; mm < 32; ++mm) o[mm] = 0.f;
    for (int j = 0; j < DD; ++j) {
        float p = s_s[i][j] * inv;
#pragma unroll
        for (int mm = 0; mm < 32; ++mm) o[mm] = fmaf(p, v_s[j][mm], o[mm]);
    }
#pragma unroll
    for (int mm = 0; mm < 32; ++mm)
        ob[((size_t)b * DD + i) * HH + hd * 32 + mm] = o[mm];
}

// ---------------- fq = h2[:, -1, :] @ Fq + fbq (M=128) --------------------
__global__ __launch_bounds__(256) void fq_kernel(
    const float* __restrict__ h2, const float* __restrict__ Fq,
    const float* __restrict__ fbq, float* __restrict__ fqb)
{
    __shared__ float A_s[16][HH];
    int tid = threadIdx.x;
    int b0 = blockIdx.x * 16;
    int col = tid & 127, rg = tid >> 7;
    for (int i = tid; i < 16 * HH; i += 256) {
        int r = i >> 7, kk = i & 127;
        A_s[r][kk] = h2[((size_t)(b0 + r) * DD + DD - 1) * HH + kk];
    }
    __syncthreads();
    float acc[8];
#pragma unroll
    for (int r = 0; r < 8; ++r) acc[r] = 0.f;
    for (int kk = 0; kk < HH; ++kk) {
        float w = Fq[kk * HH + col];
#pragma unroll
        for (int r = 0; r < 8; ++r)
            acc[r] = fmaf(A_s[rg * 8 + r][kk], w, acc[r]);
    }
    float bv = fbq[col];
#pragma unroll
    for (int r = 0; r < 8; ++r)
        fqb[(size_t)(b0 + rg * 8 + r) * HH + col] = acc[r] + bv;
}

// ---------------- final: e=tanh(fq+fk)@Fout, softmax, out=a@fv ------------
__global__ __launch_bounds__(256) void final_reduce_kernel(
    const float* __restrict__ fqb, const float* __restrict__ fkb,
    const float* __restrict__ fvb, const float* __restrict__ Fout,
    const float* __restrict__ fbout, float* __restrict__ out)
{
    int b = blockIdx.x;
    int tid = threadIdx.x;
    __shared__ float fq_s[HH], fo_s[HH], e_s[DD];
    __shared__ float red_s[256];
    if (tid < HH) {
        fq_s[tid] = fqb[(size_t)b * HH + tid];
        fo_s[tid] = Fout[tid];
    }
    __syncthreads();
    int dd = tid >> 2, sub = tid & 3;
    const float* fkrow = fkb + ((size_t)b * DD + dd) * HH + sub * 32;
    float p = 0.f;
#pragma unroll 8
    for (int mm = 0; mm < 32; ++mm)
        p = fmaf(tanhf(fq_s[sub * 32 + mm] + fkrow[mm]), fo_s[sub * 32 + mm], p);
    p += __shfl_xor(p, 1);
    p += __shfl_xor(p, 2);
    if (sub == 0) e_s[dd] = p + fbout[0];
    __syncthreads();
    if (tid < 64) {
        float e = e_s[tid];
        float mx = e;
        for (int o = 32; o; o >>= 1) mx = fmaxf(mx, __shfl_xor(mx, o));
        float pe = __expf(e - mx);
        float s = pe;
        for (int o = 32; o; o >>= 1) s += __shfl_xor(s, o);
        e_s[tid] = pe / s;
    }
    __syncthreads();
    int col = tid & 127, rg = tid >> 7;
    float acc = 0.f;
    for (int d2 = rg * 32; d2 < rg * 32 + 32; ++d2)
        acc = fmaf(e_s[d2], fvb[((size_t)b * DD + d2) * HH + col], acc);
    red_s[tid] = acc;
    __syncthreads();
    if (rg == 0)
        out[(size_t)b * HH + col] = red_s[col] + red_s[col + 128];
}

// ---------------- launch ---------------------------------------------------
extern "C" void kernel_launch(void* const* d_in, const int* in_sizes, int n_in,
                              void* d_out, int out_size, void* d_ws, size_t ws_size,
                              hipStream_t stream)
{
    const float* x    = (const float*)d_in[0];
    const int*   mask = (const int*)d_in[1];
    const float* Wih  = (const float*)d_in[2];
    const float* Whh  = (const float*)d_in[3];
    const float* bih  = (const float*)d_in[4];
    const float* bhh  = (const float*)d_in[5];
    const float* Wq = (const float*)d_in[6];   const float* bq = (const float*)d_in[7];
    const float* Wk = (const float*)d_in[8];   const float* bk = (const float*)d_in[9];
    const float* Wv = (const float*)d_in[10];  const float* bv = (const float*)d_in[11];
    const float* Wo = (const float*)d_in[12];  const float* bo = (const float*)d_in[13];
    const float* W1 = (const float*)d_in[14];  const float* b1 = (const float*)d_in[15];
    const float* W2 = (const float*)d_in[16];  const float* b2 = (const float*)d_in[17];
    const float* g1 = (const float*)d_in[18];  const float* be1 = (const float*)d_in[19];
    const float* g2 = (const float*)d_in[20];  const float* be2 = (const float*)d_in[21];
    const float* Fq = (const float*)d_in[22];  const float* fbq = (const float*)d_in[23];
    const float* Fk = (const float*)d_in[24];  const float* fbk = (const float*)d_in[25];
    const float* Fv = (const float*)d_in[26];  const float* fbv = (const float*)d_in[27];
    const float* Fout = (const float*)d_in[28]; const float* fbout = (const float*)d_in[29];
    float* out = (float*)d_out;
    float* ws  = (float*)d_ws;

    float* emb = ws;                  // 1048576
    float* qb  = ws + 1048576;
    float* kb  = ws + 2097152;
    float* vb  = ws + 3145728;
    float* ob  = ws + 4194304;
    float* h1  = ws + 5242880;
    float* a1  = ws + 6291456;        // 2097152
    float* h2  = ws + 8388608;
    float* fkb = ws + 9437184;
    float* fvb = ws + 10485760;
    float* fqb = ws + 11534336;       // +16384

    gru_mfma_kernel<<<dim3(DD, BB / 16), 256, 0, stream>>>(x, mask, Wih, Whh, bih, bhh, emb);
    qkv3_kernel<<<512, 256, 0, stream>>>(emb, Wq, bq, Wk, bk, Wv, bv, qb, kb, vb);
    attn_kernel<<<dim3(BB, NHH), 64, 0, stream>>>(qb, kb, vb, ob);
    mm_ln_kernel<128><<<512, 256, 0, stream>>>(ob, Wo, bo, emb, g1, be1, h1);
    mm_kernel<128, 256, 1><<<dim3(512, 2), 256, 0, stream>>>(h1, W1, b1, a1);
    mm_ln_kernel<256><<<512, 256, 0, stream>>>(a1, W2, b2, h1, g2, be2, h2);
    kv2_kernel<<<512, 256, 0, stream>>>(h2, Fk, fbk, Fv, fbv, fkb, fvb);
    fq_kernel<<<8, 256, 0, stream>>>(h2, Fq, fbq, fqb);
    final_reduce_kernel<<<BB, 256, 0, stream>>>(fqb, fkb, fvb, Fout, fbout, out);
}

// Round 4
// 376.959 us; speedup vs baseline: 5.5957x; 1.2899x over previous
//
#include <hip/hip_runtime.h>
#include <math.h>

#define BB 128
#define TT 64
#define DD 64
#define HH 128
#define NHH 4
#define K3H 384        // 3*H

typedef __attribute__((ext_vector_type(8))) short short8_t;   // 8 bf16
typedef __attribute__((ext_vector_type(4))) float float4_t;

__device__ __forceinline__ unsigned short f2bf(float f) {
    unsigned int u = __float_as_uint(f);
    u += 0x7fffu + ((u >> 16) & 1u);      // RNE
    return (unsigned short)(u >> 16);
}

// ---------------- per-feature GRU via bf16 MFMA ---------------------------
// grid: dim3(64 /*d*/, 8 /*batch split of 16*/), block: 512 threads (8 waves)
// wave w owns hh columns [16w, 16w+16) for all 3 gates (3 MFMA n-tiles).
__global__ __launch_bounds__(512, 4) void gru_mfma_kernel(
    const float* __restrict__ x, const int* __restrict__ mask,
    const float* __restrict__ Wih, const float* __restrict__ Whh,
    const float* __restrict__ bih, const float* __restrict__ bhh,
    float* __restrict__ emb)
{
    const int d  = blockIdx.x;
    const int b0 = blockIdx.y * 16;
    const int tid = threadIdx.x;
    const int w = tid >> 6;          // wave 0..7
    const int l = tid & 63;          // lane
    const int m = l & 15;            // A row / B n / C col index
    const int q = l >> 4;            // quad 0..3

    __shared__ __align__(16) unsigned short hbuf[2][16][136]; // +8 pad, 16B rows
    __shared__ float xs_t[TT][16];                            // transposed x
    __shared__ int tstar_s[16];

    // stage x transposed: xs_t[t][row]
    for (int idx = tid; idx < 16 * TT; idx += 512) {
        int t = idx >> 4, row = idx & 15;
        xs_t[t][row] = x[((size_t)(b0 + row) * TT + t) * DD + d];
    }
    if (tid < 16) {
        int b = b0 + tid, len = 0;
        for (int t = 0; t < TT; ++t) len += mask[b * TT + t];
        int ts = len - 1;
        if (ts < 0) ts = 0;
        if (ts > TT - 1) ts = TT - 1;
        tstar_s[tid] = ts;
    }
    for (int idx = tid; idx < 16 * 136; idx += 512)
        ((unsigned short*)hbuf)[idx] = 0;   // zero buffer 0

    // ---- W fragments (B operand), once: 3 gates x 4 k-chunks ----
    short8_t Bf[3][4];
#pragma unroll
    for (int g = 0; g < 3; ++g) {
        int kcol = g * HH + 16 * w + m;
        const float* wrow = Whh + ((size_t)d * K3H + kcol) * HH;
#pragma unroll
        for (int kc = 0; kc < 4; ++kc) {
            int j0 = kc * 32 + q * 8;
            float4 w0 = *(const float4*)(wrow + j0);
            float4 w1 = *(const float4*)(wrow + j0 + 4);
            short8_t f;
            f[0] = (short)f2bf(w0.x); f[1] = (short)f2bf(w0.y);
            f[2] = (short)f2bf(w0.z); f[3] = (short)f2bf(w0.w);
            f[4] = (short)f2bf(w1.x); f[5] = (short)f2bf(w1.y);
            f[6] = (short)f2bf(w1.z); f[7] = (short)f2bf(w1.w);
            Bf[g][kc] = f;
        }
    }

    // ---- per-lane gate constants (col = 16w + m) ----
    const int hcol = 16 * w + m;
    const float wr = Wih[d * K3H + hcol];
    const float wz = Wih[d * K3H + HH + hcol];
    const float wn = Wih[d * K3H + 2 * HH + hcol];
    const float br = bih[d * K3H + hcol] + bhh[d * K3H + hcol];
    const float bz = bih[d * K3H + HH + hcol] + bhh[d * K3H + HH + hcol];
    const float bni = bih[d * K3H + 2 * HH + hcol];
    const float bnh = bhh[d * K3H + 2 * HH + hcol];

    float hprev[4], hsel[4];
#pragma unroll
    for (int i = 0; i < 4; ++i) { hprev[i] = 0.f; hsel[i] = 0.f; }

    __syncthreads();

    int tstar4[4];
#pragma unroll
    for (int reg = 0; reg < 4; ++reg) tstar4[reg] = tstar_s[q * 4 + reg];

    for (int t = 0; t < TT; ++t) {
        const unsigned short* hb = &hbuf[t & 1][0][0];
        unsigned short* hbn = &hbuf[(t & 1) ^ 1][0][0];

        short8_t A[4];
#pragma unroll
        for (int kc = 0; kc < 4; ++kc)
            A[kc] = *(const short8_t*)(hb + m * 136 + kc * 32 + q * 8);
        float4 x4 = *(const float4*)&xs_t[t][q * 4];   // one b128 broadcast

        float4_t ar = {0.f,0.f,0.f,0.f}, az = {0.f,0.f,0.f,0.f}, an = {0.f,0.f,0.f,0.f};
#pragma unroll
        for (int kc = 0; kc < 4; ++kc) {
            ar = __builtin_amdgcn_mfma_f32_16x16x32_bf16(A[kc], Bf[0][kc], ar, 0, 0, 0);
            az = __builtin_amdgcn_mfma_f32_16x16x32_bf16(A[kc], Bf[1][kc], az, 0, 0, 0);
            an = __builtin_amdgcn_mfma_f32_16x16x32_bf16(A[kc], Bf[2][kc], an, 0, 0, 0);
        }

        const float* x4p = (const float*)&x4;
#pragma unroll
        for (int reg = 0; reg < 4; ++reg) {
            float xv = x4p[reg];
            float gr = ar[reg] + fmaf(xv, wr, br);
            float gz = az[reg] + fmaf(xv, wz, bz);
            float rg = __builtin_amdgcn_rcpf(1.f + __expf(-gr));
            float zg = __builtin_amdgcn_rcpf(1.f + __expf(-gz));
            float gnh = an[reg] + bnh;
            float gn = fmaf(rg, gnh, fmaf(xv, wn, bni));
            float tn = fmaf(-2.f, __builtin_amdgcn_rcpf(__expf(2.f * gn) + 1.f), 1.f);
            float hn = fmaf(zg, hprev[reg] - tn, tn);
            hprev[reg] = hn;
            hsel[reg] = (t == tstar4[reg]) ? hn : hsel[reg];
            hbn[(q * 4 + reg) * 136 + hcol] = f2bf(hn);
        }
        __syncthreads();
    }

#pragma unroll
    for (int reg = 0; reg < 4; ++reg)
        emb[(((size_t)(b0 + q * 4 + reg)) * DD + d) * HH + hcol] = hsel[reg];
}

// ---------------- plain matmul: C = act(A @ W + b) ------------------------
template <int KDIM, int NDIM, int RELU>
__global__ __launch_bounds__(256) void mm_kernel(
    const float* __restrict__ A, const float* __restrict__ W,
    const float* __restrict__ bias, float* __restrict__ C)
{
    __shared__ float A_s[16][KDIM];
    int tid = threadIdx.x;
    int row0 = blockIdx.x * 16;
    int col = blockIdx.y * 128 + (tid & 127);
    int rg = tid >> 7;
    for (int i = tid; i < 16 * KDIM; i += 256) {
        int r = i / KDIM, kk = i % KDIM;
        A_s[r][kk] = A[(size_t)(row0 + r) * KDIM + kk];
    }
    __syncthreads();
    float acc[8];
#pragma unroll
    for (int r = 0; r < 8; ++r) acc[r] = 0.f;
    for (int kk = 0; kk < KDIM; ++kk) {
        float w = W[kk * NDIM + col];
#pragma unroll
        for (int r = 0; r < 8; ++r)
            acc[r] = fmaf(A_s[rg * 8 + r][kk], w, acc[r]);
    }
    float bv = bias[col];
#pragma unroll
    for (int r = 0; r < 8; ++r) {
        float v = acc[r] + bv;
        if (RELU) v = v > 0.f ? v : 0.f;
        C[(size_t)(row0 + rg * 8 + r) * NDIM + col] = v;
    }
}

// ---------------- fused triple matmul q,k,v = emb @ {Wq,Wk,Wv} + b --------
__global__ __launch_bounds__(256) void qkv3_kernel(
    const float* __restrict__ A,
    const float* __restrict__ Wq, const float* __restrict__ bq,
    const float* __restrict__ Wk, const float* __restrict__ bk,
    const float* __restrict__ Wv, const float* __restrict__ bv,
    float* __restrict__ qb, float* __restrict__ kb, float* __restrict__ vb)
{
    __shared__ float A_s[16][HH];
    int tid = threadIdx.x;
    int row0 = blockIdx.x * 16;
    int col = tid & 127, rg = tid >> 7;
    for (int i = tid; i < 16 * HH; i += 256) {
        int r = i >> 7, kk = i & 127;
        A_s[r][kk] = A[(size_t)(row0 + r) * HH + kk];
    }
    __syncthreads();
    float aq[8], ak[8], av[8];
#pragma unroll
    for (int r = 0; r < 8; ++r) { aq[r] = 0.f; ak[r] = 0.f; av[r] = 0.f; }
    for (int kk = 0; kk < HH; ++kk) {
        float wq = Wq[kk * HH + col];
        float wk = Wk[kk * HH + col];
        float wv = Wv[kk * HH + col];
#pragma unroll
        for (int r = 0; r < 8; ++r) {
            float a = A_s[rg * 8 + r][kk];
            aq[r] = fmaf(a, wq, aq[r]);
            ak[r] = fmaf(a, wk, ak[r]);
            av[r] = fmaf(a, wv, av[r]);
        }
    }
    float bqv = bq[col], bkv = bk[col], bvv = bv[col];
#pragma unroll
    for (int r = 0; r < 8; ++r) {
        size_t o = (size_t)(row0 + rg * 8 + r) * HH + col;
        qb[o] = aq[r] + bqv;
        kb[o] = ak[r] + bkv;
        vb[o] = av[r] + bvv;
    }
}

// ------- fused: blocks 0..511 -> fk,fv = h2 @ {Fk,Fv}; 512..519 -> fq -----
__global__ __launch_bounds__(256) void kvq_kernel(
    const float* __restrict__ h2,
    const float* __restrict__ Fk, const float* __restrict__ fbk,
    const float* __restrict__ Fv, const float* __restrict__ fbv,
    const float* __restrict__ Fq, const float* __restrict__ fbq,
    float* __restrict__ fkb, float* __restrict__ fvb, float* __restrict__ fqb)
{
    __shared__ float A_s[16][HH];
    int tid = threadIdx.x;
    int col = tid & 127, rg = tid >> 7;
    if (blockIdx.x < 512) {
        int row0 = blockIdx.x * 16;
        for (int i = tid; i < 16 * HH; i += 256) {
            int r = i >> 7, kk = i & 127;
            A_s[r][kk] = h2[(size_t)(row0 + r) * HH + kk];
        }
        __syncthreads();
        float ak[8], av[8];
#pragma unroll
        for (int r = 0; r < 8; ++r) { ak[r] = 0.f; av[r] = 0.f; }
        for (int kk = 0; kk < HH; ++kk) {
            float wk = Fk[kk * HH + col];
            float wv = Fv[kk * HH + col];
#pragma unroll
            for (int r = 0; r < 8; ++r) {
                float a = A_s[rg * 8 + r][kk];
                ak[r] = fmaf(a, wk, ak[r]);
                av[r] = fmaf(a, wv, av[r]);
            }
        }
        float bkv = fbk[col], bvv = fbv[col];
#pragma unroll
        for (int r = 0; r < 8; ++r) {
            size_t o = (size_t)(row0 + rg * 8 + r) * HH + col;
            fkb[o] = ak[r] + bkv;
            fvb[o] = av[r] + bvv;
        }
    } else {
        int b0 = (blockIdx.x - 512) * 16;
        for (int i = tid; i < 16 * HH; i += 256) {
            int r = i >> 7, kk = i & 127;
            A_s[r][kk] = h2[((size_t)(b0 + r) * DD + DD - 1) * HH + kk];
        }
        __syncthreads();
        float acc[8];
#pragma unroll
        for (int r = 0; r < 8; ++r) acc[r] = 0.f;
        for (int kk = 0; kk < HH; ++kk) {
            float wq = Fq[kk * HH + col];
#pragma unroll
            for (int r = 0; r < 8; ++r)
                acc[r] = fmaf(A_s[rg * 8 + r][kk], wq, acc[r]);
        }
        float bv = fbq[col];
#pragma unroll
        for (int r = 0; r < 8; ++r)
            fqb[(size_t)(b0 + rg * 8 + r) * HH + col] = acc[r] + bv;
    }
}

// ---------------- matmul + residual + LayerNorm epilogue (N=128) ----------
template <int KDIM>
__global__ __launch_bounds__(256) void mm_ln_kernel(
    const float* __restrict__ A, const float* __restrict__ W,
    const float* __restrict__ bias, const float* __restrict__ res,
    const float* __restrict__ g, const float* __restrict__ be,
    float* __restrict__ C)
{
    __shared__ float A_s[16][KDIM];
    __shared__ float v_s[16][HH + 1];
    __shared__ float mv_s[16][2];
    int tid = threadIdx.x;
    int row0 = blockIdx.x * 16;
    int col = tid & 127, rg = tid >> 7;
    for (int i = tid; i < 16 * KDIM; i += 256) {
        int r = i / KDIM, kk = i % KDIM;
        A_s[r][kk] = A[(size_t)(row0 + r) * KDIM + kk];
    }
    __syncthreads();
    float acc[8];
#pragma unroll
    for (int r = 0; r < 8; ++r) acc[r] = 0.f;
    for (int kk = 0; kk < KDIM; ++kk) {
        float w = W[kk * HH + col];
#pragma unroll
        for (int r = 0; r < 8; ++r)
            acc[r] = fmaf(A_s[rg * 8 + r][kk], w, acc[r]);
    }
    float bv = bias[col];
#pragma unroll
    for (int r = 0; r < 8; ++r) {
        int row = rg * 8 + r;
        v_s[row][col] = acc[r] + bv + res[(size_t)(row0 + row) * HH + col];
    }
    __syncthreads();
    int r2 = tid >> 4, j = tid & 15;
    float s = 0.f;
#pragma unroll
    for (int c = 0; c < 8; ++c) s += v_s[r2][j * 8 + c];
    s += __shfl_xor(s, 1); s += __shfl_xor(s, 2);
    s += __shfl_xor(s, 4); s += __shfl_xor(s, 8);
    float mean = s * (1.f / 128.f);
    float vs = 0.f;
#pragma unroll
    for (int c = 0; c < 8; ++c) {
        float dv = v_s[r2][j * 8 + c] - mean;
        vs += dv * dv;
    }
    vs += __shfl_xor(vs, 1); vs += __shfl_xor(vs, 2);
    vs += __shfl_xor(vs, 4); vs += __shfl_xor(vs, 8);
    if (j == 0) {
        mv_s[r2][0] = mean;
        mv_s[r2][1] = rsqrtf(vs * (1.f / 128.f) + 1e-5f);
    }
    __syncthreads();
    float gv = g[col], bev = be[col];
#pragma unroll
    for (int r = 0; r < 8; ++r) {
        int row = rg * 8 + r;
        float mn = mv_s[row][0], rs = mv_s[row][1];
        C[(size_t)(row0 + row) * HH + col] = (v_s[row][col] - mn) * rs * gv + bev;
    }
}

// ---------------- MHA core: per (b, head) -------------------------------
__global__ __launch_bounds__(64) void attn_kernel(
    const float* __restrict__ qb, const float* __restrict__ kb,
    const float* __restrict__ vb, float* __restrict__ ob)
{
    int b = blockIdx.x, hd = blockIdx.y;
    int i = threadIdx.x;
    __shared__ float k_s[DD][32];
    __shared__ float v_s[DD][32];
    __shared__ float s_s[DD][DD + 1];
    for (int idx = i; idx < DD * 32; idx += 64) {
        int dd = idx >> 5, mm = idx & 31;
        k_s[dd][mm] = kb[((size_t)b * DD + dd) * HH + hd * 32 + mm];
        v_s[dd][mm] = vb[((size_t)b * DD + dd) * HH + hd * 32 + mm];
    }
    float qv[32];
#pragma unroll
    for (int mm = 0; mm < 32; ++mm) qv[mm] = qb[((size_t)b * DD + i) * HH + hd * 32 + mm];
    __syncthreads();
    const float scale = 0.17677669529663687f;
    float mx = -1e30f;
    for (int j = 0; j < DD; ++j) {
        float s = 0.f;
#pragma unroll
        for (int mm = 0; mm < 32; ++mm) s = fmaf(qv[mm], k_s[j][mm], s);
        s *= scale;
        s_s[i][j] = s;
        mx = fmaxf(mx, s);
    }
    float sum = 0.f;
    for (int j = 0; j < DD; ++j) {
        float p = __expf(s_s[i][j] - mx);
        s_s[i][j] = p;
        sum += p;
    }
    float inv = 1.f / sum;
    float o[32];
#pragma unroll
    for (int mm = 0; mm < 32; ++mm) o[mm] = 0.f;
    for (int j = 0; j < DD; ++j) {
        float p = s_s[i][j] * inv;
#pragma unroll
        for (int mm = 0; mm < 32; ++mm) o[mm] = fmaf(p, v_s[j][mm], o[mm]);
    }
#pragma unroll
    for (int mm = 0; mm < 32; ++mm)
        ob[((size_t)b * DD + i) * HH + hd * 32 + mm] = o[mm];
}

// ---------------- final: e=tanh(fq+fk)@Fout, softmax, out=a@fv ------------
__global__ __launch_bounds__(256) void final_reduce_kernel(
    const float* __restrict__ fqb, const float* __restrict__ fkb,
    const float* __restrict__ fvb, const float* __restrict__ Fout,
    const float* __restrict__ fbout, float* __restrict__ out)
{
    int b = blockIdx.x;
    int tid = threadIdx.x;
    __shared__ float fq_s[HH], fo_s[HH], e_s[DD];
    __shared__ float red_s[256];
    if (tid < HH) {
        fq_s[tid] = fqb[(size_t)b * HH + tid];
        fo_s[tid] = Fout[tid];
    }
    __syncthreads();
    int dd = tid >> 2, sub = tid & 3;
    const float* fkrow = fkb + ((size_t)b * DD + dd) * HH + sub * 32;
    float p = 0.f;
#pragma unroll 8
    for (int mm = 0; mm < 32; ++mm)
        p = fmaf(tanhf(fq_s[sub * 32 + mm] + fkrow[mm]), fo_s[sub * 32 + mm], p);
    p += __shfl_xor(p, 1);
    p += __shfl_xor(p, 2);
    if (sub == 0) e_s[dd] = p + fbout[0];
    __syncthreads();
    if (tid < 64) {
        float e = e_s[tid];
        float mx = e;
        for (int o = 32; o; o >>= 1) mx = fmaxf(mx, __shfl_xor(mx, o));
        float pe = __expf(e - mx);
        float s = pe;
        for (int o = 32; o; o >>= 1) s += __shfl_xor(s, o);
        e_s[tid] = pe / s;
    }
    __syncthreads();
    int col = tid & 127, rg = tid >> 7;
    float acc = 0.f;
    for (int d2 = rg * 32; d2 < rg * 32 + 32; ++d2)
        acc = fmaf(e_s[d2], fvb[((size_t)b * DD + d2) * HH + col], acc);
    red_s[tid] = acc;
    __syncthreads();
    if (rg == 0)
        out[(size_t)b * HH + col] = red_s[col] + red_s[col + 128];
}

// ---------------- launch ---------------------------------------------------
extern "C" void kernel_launch(void* const* d_in, const int* in_sizes, int n_in,
                              void* d_out, int out_size, void* d_ws, size_t ws_size,
                              hipStream_t stream)
{
    const float* x    = (const float*)d_in[0];
    const int*   mask = (const int*)d_in[1];
    const float* Wih  = (const float*)d_in[2];
    const float* Whh  = (const float*)d_in[3];
    const float* bih  = (const float*)d_in[4];
    const float* bhh  = (const float*)d_in[5];
    const float* Wq = (const float*)d_in[6];   const float* bq = (const float*)d_in[7];
    const float* Wk = (const float*)d_in[8];   const float* bk = (const float*)d_in[9];
    const float* Wv = (const float*)d_in[10];  const float* bv = (const float*)d_in[11];
    const float* Wo = (const float*)d_in[12];  const float* bo = (const float*)d_in[13];
    const float* W1 = (const float*)d_in[14];  const float* b1 = (const float*)d_in[15];
    const float* W2 = (const float*)d_in[16];  const float* b2 = (const float*)d_in[17];
    const float* g1 = (const float*)d_in[18];  const float* be1 = (const float*)d_in[19];
    const float* g2 = (const float*)d_in[20];  const float* be2 = (const float*)d_in[21];
    const float* Fq = (const float*)d_in[22];  const float* fbq = (const float*)d_in[23];
    const float* Fk = (const float*)d_in[24];  const float* fbk = (const float*)d_in[25];
    const float* Fv = (const float*)d_in[26];  const float* fbv = (const float*)d_in[27];
    const float* Fout = (const float*)d_in[28]; const float* fbout = (const float*)d_in[29];
    float* out = (float*)d_out;
    float* ws  = (float*)d_ws;

    float* emb = ws;                  // 1048576
    float* qb  = ws + 1048576;
    float* kb  = ws + 2097152;
    float* vb  = ws + 3145728;
    float* ob  = ws + 4194304;
    float* h1  = ws + 5242880;
    float* a1  = ws + 6291456;        // 2097152
    float* h2  = ws + 8388608;
    float* fkb = ws + 9437184;
    float* fvb = ws + 10485760;
    float* fqb = ws + 11534336;       // +16384

    gru_mfma_kernel<<<dim3(DD, BB / 16), 512, 0, stream>>>(x, mask, Wih, Whh, bih, bhh, emb);
    qkv3_kernel<<<512, 256, 0, stream>>>(emb, Wq, bq, Wk, bk, Wv, bv, qb, kb, vb);
    attn_kernel<<<dim3(BB, NHH), 64, 0, stream>>>(qb, kb, vb, ob);
    mm_ln_kernel<128><<<512, 256, 0, stream>>>(ob, Wo, bo, emb, g1, be1, h1);
    mm_kernel<128, 256, 1><<<dim3(512, 2), 256, 0, stream>>>(h1, W1, b1, a1);
    mm_ln_kernel<256><<<512, 256, 0, stream>>>(a1, W2, b2, h1, g2, be2, h2);
    kvq_kernel<<<520, 256, 0, stream>>>(h2, Fk, fbk, Fv, fbv, Fq, fbq, fkb, fvb, fqb);
    final_reduce_kernel<<<BB, 256, 0, stream>>>(fqb, fkb, fvb, Fout, fbout, out);
}

// Round 6
// 356.775 us; speedup vs baseline: 5.9122x; 1.0566x over previous
//
#include <hip/hip_runtime.h>
#include <math.h>

#define BB 128
#define TT 64
#define DD 64
#define HH 128
#define NHH 4
#define K3H 384        // 3*H

typedef __attribute__((ext_vector_type(8))) short short8_t;   // 8 bf16
typedef __attribute__((ext_vector_type(4))) float float4_t;

#define LOG2E 1.4426950408889634f

__device__ __forceinline__ unsigned short f2bf(float f) {
    unsigned int u = __float_as_uint(f);
    u += 0x7fffu + ((u >> 16) & 1u);      // RNE
    return (unsigned short)(u >> 16);
}

__device__ __forceinline__ unsigned pack_bf2(float lo, float hi) {
    return (unsigned)f2bf(lo) | ((unsigned)f2bf(hi) << 16);
}

// ---------------- per-feature GRU via bf16 MFMA (transposed C) ------------
// grid: dim3(64 /*d*/, 8 /*batch split of 16*/), block: 512 threads (8 waves)
// D = Wgate (A, 16 hidden cols x K=128) * h^T (B, K x 16 batch)
// C: col(lane&15) = batch row, row(q*4+reg) = hidden col -> 4 consecutive
// hidden cols per lane => packed bf16 writeback, vectorized emb store.
__global__ __launch_bounds__(512, 4) void gru_mfma_kernel(
    const float* __restrict__ x, const int* __restrict__ mask,
    const float* __restrict__ Wih, const float* __restrict__ Whh,
    const float* __restrict__ bih, const float* __restrict__ bhh,
    float* __restrict__ emb)
{
    const int d  = blockIdx.x;
    const int b0 = blockIdx.y * 16;
    const int tid = threadIdx.x;
    const int w = tid >> 6;          // wave 0..7
    const int l = tid & 63;          // lane
    const int m = l & 15;            // batch row (B-frag n, C col)
    const int q = l >> 4;            // quad 0..3

    __shared__ __align__(16) unsigned short hbuf[2][16][136]; // +8 pad
    __shared__ float xs_t[TT][16];                            // xs_t[t][row]
    __shared__ int tstar_s[16];

    for (int idx = tid; idx < 16 * TT; idx += 512) {
        int t = idx >> 4, row = idx & 15;
        xs_t[t][row] = x[((size_t)(b0 + row) * TT + t) * DD + d];
    }
    if (tid < 16) {
        int b = b0 + tid, len = 0;
        for (int t = 0; t < TT; ++t) len += mask[b * TT + t];
        int ts = len - 1;
        if (ts < 0) ts = 0;
        if (ts > TT - 1) ts = TT - 1;
        tstar_s[tid] = ts;
    }
    for (int idx = tid; idx < 16 * 136; idx += 512)
        ((unsigned short*)hbuf)[idx] = 0;   // zero buffer 0

    // ---- W fragments (A operand), once: 3 gates x 4 k-chunks -------------
    // scale folded in: r,z by -log2e (sigmoid via exp2), n by 2*log2e (tanh)
    short8_t Wf[3][4];
#pragma unroll
    for (int g = 0; g < 3; ++g) {
        float sc = (g == 2) ? (2.f * LOG2E) : (-LOG2E);
        int kcol = g * HH + 16 * w + m;          // A row = hidden col
        const float* wrow = Whh + ((size_t)d * K3H + kcol) * HH;
#pragma unroll
        for (int kc = 0; kc < 4; ++kc) {
            int j0 = kc * 32 + q * 8;
            float4 w0 = *(const float4*)(wrow + j0);
            float4 w1 = *(const float4*)(wrow + j0 + 4);
            short8_t f;
            f[0] = (short)f2bf(w0.x * sc); f[1] = (short)f2bf(w0.y * sc);
            f[2] = (short)f2bf(w0.z * sc); f[3] = (short)f2bf(w0.w * sc);
            f[4] = (short)f2bf(w1.x * sc); f[5] = (short)f2bf(w1.y * sc);
            f[6] = (short)f2bf(w1.z * sc); f[7] = (short)f2bf(w1.w * sc);
            Wf[g][kc] = f;
        }
    }

    // ---- per-lane gate constants: 4 consecutive hidden cols --------------
    const int hcol0 = 16 * w + q * 4;
    float4 wr4 = *(const float4*)&Wih[d * K3H + hcol0];
    float4 wz4 = *(const float4*)&Wih[d * K3H + HH + hcol0];
    float4 wn4 = *(const float4*)&Wih[d * K3H + 2 * HH + hcol0];
    float4 br4 = *(const float4*)&bih[d * K3H + hcol0];
    float4 bz4 = *(const float4*)&bih[d * K3H + HH + hcol0];
    float4 bni4 = *(const float4*)&bih[d * K3H + 2 * HH + hcol0];
    float4 bhr4 = *(const float4*)&bhh[d * K3H + hcol0];
    float4 bhz4 = *(const float4*)&bhh[d * K3H + HH + hcol0];
    float4 bnh4 = *(const float4*)&bhh[d * K3H + 2 * HH + hcol0];
    float brs[4], bzs[4], bnis[4], bnhs[4], wrs[4], wzs[4], wns[4];
#pragma unroll
    for (int r = 0; r < 4; ++r) {
        wrs[r] = -LOG2E * ((const float*)&wr4)[r];
        wzs[r] = -LOG2E * ((const float*)&wz4)[r];
        wns[r] = 2.f * LOG2E * ((const float*)&wn4)[r];
        brs[r] = -LOG2E * (((const float*)&br4)[r] + ((const float*)&bhr4)[r]);
        bzs[r] = -LOG2E * (((const float*)&bz4)[r] + ((const float*)&bhz4)[r]);
        bnis[r] = 2.f * LOG2E * ((const float*)&bni4)[r];
        bnhs[r] = 2.f * LOG2E * ((const float*)&bnh4)[r];
    }

    float hprev[4];
#pragma unroll
    for (int i = 0; i < 4; ++i) hprev[i] = 0.f;

    __syncthreads();
    const int tstar_m = tstar_s[m];
    float* embp = emb + (((size_t)(b0 + m)) * DD + d) * HH + hcol0;

    for (int t = 0; t < TT; ++t) {
        const unsigned short* hb = &hbuf[t & 1][0][0];
        unsigned short* hbn = &hbuf[(t & 1) ^ 1][0][0];

        // B fragments: lane holds h[batch=m][kc*32 + q*8 + 0..7]
        short8_t hf[4];
#pragma unroll
        for (int kc = 0; kc < 4; ++kc)
            hf[kc] = *(const short8_t*)(hb + m * 136 + kc * 32 + q * 8);
        float xv = xs_t[t][m];

        float4_t ar = {0.f,0.f,0.f,0.f}, az = {0.f,0.f,0.f,0.f}, an = {0.f,0.f,0.f,0.f};
#pragma unroll
        for (int kc = 0; kc < 4; ++kc) {
            ar = __builtin_amdgcn_mfma_f32_16x16x32_bf16(Wf[0][kc], hf[kc], ar, 0, 0, 0);
            az = __builtin_amdgcn_mfma_f32_16x16x32_bf16(Wf[1][kc], hf[kc], az, 0, 0, 0);
            an = __builtin_amdgcn_mfma_f32_16x16x32_bf16(Wf[2][kc], hf[kc], an, 0, 0, 0);
        }

        float hn4[4];
#pragma unroll
        for (int reg = 0; reg < 4; ++reg) {
            float grs = ar[reg] + fmaf(xv, wrs[reg], brs[reg]);
            float gzs = az[reg] + fmaf(xv, wzs[reg], bzs[reg]);
            float rg = __builtin_amdgcn_rcpf(1.f + __builtin_amdgcn_exp2f(grs));
            float zg = __builtin_amdgcn_rcpf(1.f + __builtin_amdgcn_exp2f(gzs));
            float gns = fmaf(rg, an[reg] + bnhs[reg], fmaf(xv, wns[reg], bnis[reg]));
            float tn = fmaf(-2.f, __builtin_amdgcn_rcpf(__builtin_amdgcn_exp2f(gns) + 1.f), 1.f);
            float hn = fmaf(zg, hprev[reg] - tn, tn);
            hprev[reg] = hn;
            hn4[reg] = hn;
        }
        // packed bf16 writeback: 4 consecutive cols, one 8B store
        uint2 uu;
        uu.x = pack_bf2(hn4[0], hn4[1]);
        uu.y = pack_bf2(hn4[2], hn4[3]);
        *(uint2*)(hbn + m * 136 + hcol0) = uu;
        if (t == tstar_m) {
            float4 hv; hv.x = hn4[0]; hv.y = hn4[1]; hv.z = hn4[2]; hv.w = hn4[3];
            *(float4*)embp = hv;
        }
        __syncthreads();
    }
}

// ---------------- plain matmul: C = act(A @ W + b) ------------------------
template <int KDIM, int NDIM, int RELU>
__global__ __launch_bounds__(256) void mm_kernel(
    const float* __restrict__ A, const float* __restrict__ W,
    const float* __restrict__ bias, float* __restrict__ C)
{
    __shared__ float A_s[16][KDIM];
    int tid = threadIdx.x;
    int row0 = blockIdx.x * 16;
    int col = blockIdx.y * 128 + (tid & 127);
    int rg = tid >> 7;
    for (int i = tid; i < 16 * KDIM; i += 256) {
        int r = i / KDIM, kk = i % KDIM;
        A_s[r][kk] = A[(size_t)(row0 + r) * KDIM + kk];
    }
    __syncthreads();
    float acc[8];
#pragma unroll
    for (int r = 0; r < 8; ++r) acc[r] = 0.f;
#pragma unroll 8
    for (int kk = 0; kk < KDIM; ++kk) {
        float w = W[kk * NDIM + col];
#pragma unroll
        for (int r = 0; r < 8; ++r)
            acc[r] = fmaf(A_s[rg * 8 + r][kk], w, acc[r]);
    }
    float bv = bias[col];
#pragma unroll
    for (int r = 0; r < 8; ++r) {
        float v = acc[r] + bv;
        if (RELU) v = v > 0.f ? v : 0.f;
        C[(size_t)(row0 + rg * 8 + r) * NDIM + col] = v;
    }
}

// ---------------- fused triple matmul q,k,v = emb @ {Wq,Wk,Wv} + b --------
__global__ __launch_bounds__(256) void qkv3_kernel(
    const float* __restrict__ A,
    const float* __restrict__ Wq, const float* __restrict__ bq,
    const float* __restrict__ Wk, const float* __restrict__ bk,
    const float* __restrict__ Wv, const float* __restrict__ bv,
    float* __restrict__ qb, float* __restrict__ kb, float* __restrict__ vb)
{
    __shared__ float A_s[16][HH];
    int tid = threadIdx.x;
    int row0 = blockIdx.x * 16;
    int col = tid & 127, rg = tid >> 7;
    for (int i = tid; i < 16 * HH; i += 256) {
        int r = i >> 7, kk = i & 127;
        A_s[r][kk] = A[(size_t)(row0 + r) * HH + kk];
    }
    __syncthreads();
    float aq[8], ak[8], av[8];
#pragma unroll
    for (int r = 0; r < 8; ++r) { aq[r] = 0.f; ak[r] = 0.f; av[r] = 0.f; }
#pragma unroll 4
    for (int kk = 0; kk < HH; ++kk) {
        float wq = Wq[kk * HH + col];
        float wk = Wk[kk * HH + col];
        float wv = Wv[kk * HH + col];
#pragma unroll
        for (int r = 0; r < 8; ++r) {
            float a = A_s[rg * 8 + r][kk];
            aq[r] = fmaf(a, wq, aq[r]);
            ak[r] = fmaf(a, wk, ak[r]);
            av[r] = fmaf(a, wv, av[r]);
        }
    }
    float bqv = bq[col], bkv = bk[col], bvv = bv[col];
#pragma unroll
    for (int r = 0; r < 8; ++r) {
        size_t o = (size_t)(row0 + rg * 8 + r) * HH + col;
        qb[o] = aq[r] + bqv;
        kb[o] = ak[r] + bkv;
        vb[o] = av[r] + bvv;
    }
}

// ------- fused: blocks 0..511 -> fk,fv = h2 @ {Fk,Fv}; 512..519 -> fq -----
__global__ __launch_bounds__(256) void kvq_kernel(
    const float* __restrict__ h2,
    const float* __restrict__ Fk, const float* __restrict__ fbk,
    const float* __restrict__ Fv, const float* __restrict__ fbv,
    const float* __restrict__ Fq, const float* __restrict__ fbq,
    float* __restrict__ fkb, float* __restrict__ fvb, float* __restrict__ fqb)
{
    __shared__ float A_s[16][HH];
    int tid = threadIdx.x;
    int col = tid & 127, rg = tid >> 7;
    if (blockIdx.x < 512) {
        int row0 = blockIdx.x * 16;
        for (int i = tid; i < 16 * HH; i += 256) {
            int r = i >> 7, kk = i & 127;
            A_s[r][kk] = h2[(size_t)(row0 + r) * HH + kk];
        }
        __syncthreads();
        float ak[8], av[8];
#pragma unroll
        for (int r = 0; r < 8; ++r) { ak[r] = 0.f; av[r] = 0.f; }
#pragma unroll 8
        for (int kk = 0; kk < HH; ++kk) {
            float wk = Fk[kk * HH + col];
            float wv = Fv[kk * HH + col];
#pragma unroll
            for (int r = 0; r < 8; ++r) {
                float a = A_s[rg * 8 + r][kk];
                ak[r] = fmaf(a, wk, ak[r]);
                av[r] = fmaf(a, wv, av[r]);
            }
        }
        float bkv = fbk[col], bvv = fbv[col];
#pragma unroll
        for (int r = 0; r < 8; ++r) {
            size_t o = (size_t)(row0 + rg * 8 + r) * HH + col;
            fkb[o] = ak[r] + bkv;
            fvb[o] = av[r] + bvv;
        }
    } else {
        int b0 = (blockIdx.x - 512) * 16;
        for (int i = tid; i < 16 * HH; i += 256) {
            int r = i >> 7, kk = i & 127;
            A_s[r][kk] = h2[((size_t)(b0 + r) * DD + DD - 1) * HH + kk];
        }
        __syncthreads();
        float acc[8];
#pragma unroll
        for (int r = 0; r < 8; ++r) acc[r] = 0.f;
#pragma unroll 8
        for (int kk = 0; kk < HH; ++kk) {
            float wq = Fq[kk * HH + col];
#pragma unroll
            for (int r = 0; r < 8; ++r)
                acc[r] = fmaf(A_s[rg * 8 + r][kk], wq, acc[r]);
        }
        float bv = fbq[col];
#pragma unroll
        for (int r = 0; r < 8; ++r)
            fqb[(size_t)(b0 + rg * 8 + r) * HH + col] = acc[r] + bv;
    }
}

// ---------------- matmul + residual + LayerNorm epilogue (N=128) ----------
template <int KDIM>
__global__ __launch_bounds__(256) void mm_ln_kernel(
    const float* __restrict__ A, const float* __restrict__ W,
    const float* __restrict__ bias, const float* __restrict__ res,
    const float* __restrict__ g, const float* __restrict__ be,
    float* __restrict__ C)
{
    __shared__ float A_s[16][KDIM];
    __shared__ float v_s[16][HH + 1];
    __shared__ float mv_s[16][2];
    int tid = threadIdx.x;
    int row0 = blockIdx.x * 16;
    int col = tid & 127, rg = tid >> 7;
    for (int i = tid; i < 16 * KDIM; i += 256) {
        int r = i / KDIM, kk = i % KDIM;
        A_s[r][kk] = A[(size_t)(row0 + r) * KDIM + kk];
    }
    __syncthreads();
    float acc[8];
#pragma unroll
    for (int r = 0; r < 8; ++r) acc[r] = 0.f;
#pragma unroll 8
    for (int kk = 0; kk < KDIM; ++kk) {
        float w = W[kk * HH + col];
#pragma unroll
        for (int r = 0; r < 8; ++r)
            acc[r] = fmaf(A_s[rg * 8 + r][kk], w, acc[r]);
    }
    float bv = bias[col];
#pragma unroll
    for (int r = 0; r < 8; ++r) {
        int row = rg * 8 + r;
        v_s[row][col] = acc[r] + bv + res[(size_t)(row0 + row) * HH + col];
    }
    __syncthreads();
    int r2 = tid >> 4, j = tid & 15;
    float s = 0.f;
#pragma unroll
    for (int c = 0; c < 8; ++c) s += v_s[r2][j * 8 + c];
    s += __shfl_xor(s, 1); s += __shfl_xor(s, 2);
    s += __shfl_xor(s, 4); s += __shfl_xor(s, 8);
    float mean = s * (1.f / 128.f);
    float vs = 0.f;
#pragma unroll
    for (int c = 0; c < 8; ++c) {
        float dv = v_s[r2][j * 8 + c] - mean;
        vs += dv * dv;
    }
    vs += __shfl_xor(vs, 1); vs += __shfl_xor(vs, 2);
    vs += __shfl_xor(vs, 4); vs += __shfl_xor(vs, 8);
    if (j == 0) {
        mv_s[r2][0] = mean;
        mv_s[r2][1] = rsqrtf(vs * (1.f / 128.f) + 1e-5f);
    }
    __syncthreads();
    float gv = g[col], bev = be[col];
#pragma unroll
    for (int r = 0; r < 8; ++r) {
        int row = rg * 8 + r;
        float mn = mv_s[row][0], rs = mv_s[row][1];
        C[(size_t)(row0 + row) * HH + col] = (v_s[row][col] - mn) * rs * gv + bev;
    }
}

// ---------------- MHA core v2: block (b, head), 256 threads ---------------
__global__ __launch_bounds__(256) void attn_kernel(
    const float* __restrict__ qb, const float* __restrict__ kb,
    const float* __restrict__ vb, float* __restrict__ ob)
{
    int b = blockIdx.x & (BB - 1), hd = blockIdx.x >> 7;
    int tid = threadIdx.x;
    int qrow = tid & 63, qq = tid >> 6;      // quarter (wave-uniform)
    __shared__ float k_s[DD][32];
    __shared__ float v_s[DD][32];
    __shared__ float s_s[DD][65];
    __shared__ float mxp_s[DD][4];
    __shared__ float smp_s[DD][4];
    const float scale = 0.17677669529663687f;  // 1/sqrt(32)
    for (int idx = tid; idx < DD * 8; idx += 256) {
        int row = idx >> 3, c4 = (idx & 7) * 4;
        float4 kv = *(const float4*)&kb[((size_t)b * DD + row) * HH + hd * 32 + c4];
        float4 vv = *(const float4*)&vb[((size_t)b * DD + row) * HH + hd * 32 + c4];
        kv.x *= scale; kv.y *= scale; kv.z *= scale; kv.w *= scale;
        *(float4*)&k_s[row][c4] = kv;
        *(float4*)&v_s[row][c4] = vv;
    }
    float qv[32];
    const float* qp = qb + ((size_t)b * DD + qrow) * HH + hd * 32;
#pragma unroll
    for (int c4 = 0; c4 < 8; ++c4) {
        float4 t = *(const float4*)(qp + c4 * 4);
        qv[c4 * 4 + 0] = t.x; qv[c4 * 4 + 1] = t.y;
        qv[c4 * 4 + 2] = t.z; qv[c4 * 4 + 3] = t.w;
    }
    __syncthreads();
    float mx = -1e30f;
#pragma unroll
    for (int j0 = 0; j0 < 16; ++j0) {
        int j = qq * 16 + j0;
        float s = 0.f;
#pragma unroll
        for (int mm = 0; mm < 32; ++mm) s = fmaf(qv[mm], k_s[j][mm], s);
        s_s[qrow][j] = s;
        mx = fmaxf(mx, s);
    }
    mxp_s[qrow][qq] = mx;
    __syncthreads();
    float m4 = fmaxf(fmaxf(mxp_s[qrow][0], mxp_s[qrow][1]),
                     fmaxf(mxp_s[qrow][2], mxp_s[qrow][3]));
    float sum = 0.f;
#pragma unroll
    for (int j0 = 0; j0 < 16; ++j0) {
        int j = qq * 16 + j0;
        float p = __expf(s_s[qrow][j] - m4);
        s_s[qrow][j] = p;
        sum += p;
    }
    smp_s[qrow][qq] = sum;
    __syncthreads();
    float inv = __builtin_amdgcn_rcpf(smp_s[qrow][0] + smp_s[qrow][1] +
                                      smp_s[qrow][2] + smp_s[qrow][3]);
    float o[8];
#pragma unroll
    for (int c = 0; c < 8; ++c) o[c] = 0.f;
    for (int j = 0; j < DD; ++j) {
        float p = s_s[qrow][j];
#pragma unroll
        for (int c = 0; c < 8; ++c) o[c] = fmaf(p, v_s[j][qq * 8 + c], o[c]);
    }
    float* op = ob + ((size_t)b * DD + qrow) * HH + hd * 32 + qq * 8;
    float4 o0, o1;
    o0.x = o[0] * inv; o0.y = o[1] * inv; o0.z = o[2] * inv; o0.w = o[3] * inv;
    o1.x = o[4] * inv; o1.y = o[5] * inv; o1.z = o[6] * inv; o1.w = o[7] * inv;
    *(float4*)op = o0;
    *(float4*)(op + 4) = o1;
}

// ---------------- final: e=tanh(fq+fk)@Fout, softmax, out=a@fv ------------
__global__ __launch_bounds__(256) void final_reduce_kernel(
    const float* __restrict__ fqb, const float* __restrict__ fkb,
    const float* __restrict__ fvb, const float* __restrict__ Fout,
    const float* __restrict__ fbout, float* __restrict__ out)
{
    int b = blockIdx.x;
    int tid = threadIdx.x;
    __shared__ float fq_s[HH], fo_s[HH], e_s[DD];
    __shared__ float red_s[256];
    if (tid < HH) {
        fq_s[tid] = fqb[(size_t)b * HH + tid];
        fo_s[tid] = Fout[tid];
    }
    __syncthreads();
    int dd = tid >> 2, sub = tid & 3;
    const float* fkrow = fkb + ((size_t)b * DD + dd) * HH + sub * 32;
    float p = 0.f;
#pragma unroll 8
    for (int mm = 0; mm < 32; ++mm)
        p = fmaf(tanhf(fq_s[sub * 32 + mm] + fkrow[mm]), fo_s[sub * 32 + mm], p);
    p += __shfl_xor(p, 1);
    p += __shfl_xor(p, 2);
    if (sub == 0) e_s[dd] = p + fbout[0];
    __syncthreads();
    if (tid < 64) {
        float e = e_s[tid];
        float mx = e;
        for (int o = 32; o; o >>= 1) mx = fmaxf(mx, __shfl_xor(mx, o));
        float pe = __expf(e - mx);
        float s = pe;
        for (int o = 32; o; o >>= 1) s += __shfl_xor(s, o);
        e_s[tid] = pe / s;
    }
    __syncthreads();
    int col = tid & 127, rg = tid >> 7;
    float acc = 0.f;
    for (int d2 = rg * 32; d2 < rg * 32 + 32; ++d2)
        acc = fmaf(e_s[d2], fvb[((size_t)b * DD + d2) * HH + col], acc);
    red_s[tid] = acc;
    __syncthreads();
    if (rg == 0)
        out[(size_t)b * HH + col] = red_s[col] + red_s[col + 128];
}

// ---------------- launch ---------------------------------------------------
extern "C" void kernel_launch(void* const* d_in, const int* in_sizes, int n_in,
                              void* d_out, int out_size, void* d_ws, size_t ws_size,
                              hipStream_t stream)
{
    const float* x    = (const float*)d_in[0];
    const int*   mask = (const int*)d_in[1];
    const float* Wih  = (const float*)d_in[2];
    const float* Whh  = (const float*)d_in[3];
    const float* bih  = (const float*)d_in[4];
    const float* bhh  = (const float*)d_in[5];
    const float* Wq = (const float*)d_in[6];   const float* bq = (const float*)d_in[7];
    const float* Wk = (const float*)d_in[8];   const float* bk = (const float*)d_in[9];
    const float* Wv = (const float*)d_in[10];  const float* bv = (const float*)d_in[11];
    const float* Wo = (const float*)d_in[12];  const float* bo = (const float*)d_in[13];
    const float* W1 = (const float*)d_in[14];  const float* b1 = (const float*)d_in[15];
    const float* W2 = (const float*)d_in[16];  const float* b2 = (const float*)d_in[17];
    const float* g1 = (const float*)d_in[18];  const float* be1 = (const float*)d_in[19];
    const float* g2 = (const float*)d_in[20];  const float* be2 = (const float*)d_in[21];
    const float* Fq = (const float*)d_in[22];  const float* fbq = (const float*)d_in[23];
    const float* Fk = (const float*)d_in[24];  const float* fbk = (const float*)d_in[25];
    const float* Fv = (const float*)d_in[26];  const float* fbv = (const float*)d_in[27];
    const float* Fout = (const float*)d_in[28]; const float* fbout = (const float*)d_in[29];
    float* out = (float*)d_out;
    float* ws  = (float*)d_ws;

    float* emb = ws;                  // 1048576
    float* qb  = ws + 1048576;
    float* kb  = ws + 2097152;
    float* vb  = ws + 3145728;
    float* ob  = ws + 4194304;
    float* h1  = ws + 5242880;
    float* a1  = ws + 6291456;        // 2097152
    float* h2  = ws + 8388608;
    float* fkb = ws + 9437184;
    float* fvb = ws + 10485760;
    float* fqb = ws + 11534336;       // +16384

    gru_mfma_kernel<<<dim3(DD, BB / 16), 512, 0, stream>>>(x, mask, Wih, Whh, bih, bhh, emb);
    qkv3_kernel<<<512, 256, 0, stream>>>(emb, Wq, bq, Wk, bk, Wv, bv, qb, kb, vb);
    attn_kernel<<<BB * NHH, 256, 0, stream>>>(qb, kb, vb, ob);
    mm_ln_kernel<128><<<512, 256, 0, stream>>>(ob, Wo, bo, emb, g1, be1, h1);
    mm_kernel<128, 256, 1><<<dim3(512, 2), 256, 0, stream>>>(h1, W1, b1, a1);
    mm_ln_kernel<256><<<512, 256, 0, stream>>>(a1, W2, b2, h1, g2, be2, h2);
    kvq_kernel<<<520, 256, 0, stream>>>(h2, Fk, fbk, Fv, fbv, Fq, fbq, fkb, fvb, fqb);
    final_reduce_kernel<<<BB, 256, 0, stream>>>(fqb, fkb, fvb, Fout, fbout, out);
}

// Round 7
// 290.753 us; speedup vs baseline: 7.2548x; 1.2271x over previous
//
#include <hip/hip_runtime.h>
#include <math.h>

#define BB 128
#define TT 64
#define DD 64
#define HH 128
#define NHH 4
#define K3H 384        // 3*H

typedef __attribute__((ext_vector_type(8))) short short8_t;   // 8 bf16
typedef __attribute__((ext_vector_type(4))) float float4_t;

#define LOG2E 1.4426950408889634f

__device__ __forceinline__ unsigned short f2bf(float f) {
    unsigned int u = __float_as_uint(f);
    u += 0x7fffu + ((u >> 16) & 1u);      // RNE
    return (unsigned short)(u >> 16);
}

__device__ __forceinline__ unsigned pack_bf2(float lo, float hi) {
    return (unsigned)f2bf(lo) | ((unsigned)f2bf(hi) << 16);
}

// ---------------- per-feature GRU via bf16 MFMA (transposed C) ------------
// (unchanged from round 6 — ~103 us, multi-pipe bound)
__global__ __launch_bounds__(512, 4) void gru_mfma_kernel(
    const float* __restrict__ x, const int* __restrict__ mask,
    const float* __restrict__ Wih, const float* __restrict__ Whh,
    const float* __restrict__ bih, const float* __restrict__ bhh,
    float* __restrict__ emb)
{
    const int d  = blockIdx.x;
    const int b0 = blockIdx.y * 16;
    const int tid = threadIdx.x;
    const int w = tid >> 6;          // wave 0..7
    const int l = tid & 63;          // lane
    const int m = l & 15;            // batch row (B-frag n, C col)
    const int q = l >> 4;            // quad 0..3

    __shared__ __align__(16) unsigned short hbuf[2][16][136]; // +8 pad
    __shared__ float xs_t[TT][16];                            // xs_t[t][row]
    __shared__ int tstar_s[16];

    for (int idx = tid; idx < 16 * TT; idx += 512) {
        int t = idx >> 4, row = idx & 15;
        xs_t[t][row] = x[((size_t)(b0 + row) * TT + t) * DD + d];
    }
    if (tid < 16) {
        int b = b0 + tid, len = 0;
        for (int t = 0; t < TT; ++t) len += mask[b * TT + t];
        int ts = len - 1;
        if (ts < 0) ts = 0;
        if (ts > TT - 1) ts = TT - 1;
        tstar_s[tid] = ts;
    }
    for (int idx = tid; idx < 16 * 136; idx += 512)
        ((unsigned short*)hbuf)[idx] = 0;   // zero buffer 0

    short8_t Wf[3][4];
#pragma unroll
    for (int g = 0; g < 3; ++g) {
        float sc = (g == 2) ? (2.f * LOG2E) : (-LOG2E);
        int kcol = g * HH + 16 * w + m;          // A row = hidden col
        const float* wrow = Whh + ((size_t)d * K3H + kcol) * HH;
#pragma unroll
        for (int kc = 0; kc < 4; ++kc) {
            int j0 = kc * 32 + q * 8;
            float4 w0 = *(const float4*)(wrow + j0);
            float4 w1 = *(const float4*)(wrow + j0 + 4);
            short8_t f;
            f[0] = (short)f2bf(w0.x * sc); f[1] = (short)f2bf(w0.y * sc);
            f[2] = (short)f2bf(w0.z * sc); f[3] = (short)f2bf(w0.w * sc);
            f[4] = (short)f2bf(w1.x * sc); f[5] = (short)f2bf(w1.y * sc);
            f[6] = (short)f2bf(w1.z * sc); f[7] = (short)f2bf(w1.w * sc);
            Wf[g][kc] = f;
        }
    }

    const int hcol0 = 16 * w + q * 4;
    float4 wr4 = *(const float4*)&Wih[d * K3H + hcol0];
    float4 wz4 = *(const float4*)&Wih[d * K3H + HH + hcol0];
    float4 wn4 = *(const float4*)&Wih[d * K3H + 2 * HH + hcol0];
    float4 br4 = *(const float4*)&bih[d * K3H + hcol0];
    float4 bz4 = *(const float4*)&bih[d * K3H + HH + hcol0];
    float4 bni4 = *(const float4*)&bih[d * K3H + 2 * HH + hcol0];
    float4 bhr4 = *(const float4*)&bhh[d * K3H + hcol0];
    float4 bhz4 = *(const float4*)&bhh[d * K3H + HH + hcol0];
    float4 bnh4 = *(const float4*)&bhh[d * K3H + 2 * HH + hcol0];
    float brs[4], bzs[4], bnis[4], bnhs[4], wrs[4], wzs[4], wns[4];
#pragma unroll
    for (int r = 0; r < 4; ++r) {
        wrs[r] = -LOG2E * ((const float*)&wr4)[r];
        wzs[r] = -LOG2E * ((const float*)&wz4)[r];
        wns[r] = 2.f * LOG2E * ((const float*)&wn4)[r];
        brs[r] = -LOG2E * (((const float*)&br4)[r] + ((const float*)&bhr4)[r]);
        bzs[r] = -LOG2E * (((const float*)&bz4)[r] + ((const float*)&bhz4)[r]);
        bnis[r] = 2.f * LOG2E * ((const float*)&bni4)[r];
        bnhs[r] = 2.f * LOG2E * ((const float*)&bnh4)[r];
    }

    float hprev[4];
#pragma unroll
    for (int i = 0; i < 4; ++i) hprev[i] = 0.f;

    __syncthreads();
    const int tstar_m = tstar_s[m];
    float* embp = emb + (((size_t)(b0 + m)) * DD + d) * HH + hcol0;

    for (int t = 0; t < TT; ++t) {
        const unsigned short* hb = &hbuf[t & 1][0][0];
        unsigned short* hbn = &hbuf[(t & 1) ^ 1][0][0];

        short8_t hf[4];
#pragma unroll
        for (int kc = 0; kc < 4; ++kc)
            hf[kc] = *(const short8_t*)(hb + m * 136 + kc * 32 + q * 8);
        float xv = xs_t[t][m];

        float4_t ar = {0.f,0.f,0.f,0.f}, az = {0.f,0.f,0.f,0.f}, an = {0.f,0.f,0.f,0.f};
#pragma unroll
        for (int kc = 0; kc < 4; ++kc) {
            ar = __builtin_amdgcn_mfma_f32_16x16x32_bf16(Wf[0][kc], hf[kc], ar, 0, 0, 0);
            az = __builtin_amdgcn_mfma_f32_16x16x32_bf16(Wf[1][kc], hf[kc], az, 0, 0, 0);
            an = __builtin_amdgcn_mfma_f32_16x16x32_bf16(Wf[2][kc], hf[kc], an, 0, 0, 0);
        }

        float hn4[4];
#pragma unroll
        for (int reg = 0; reg < 4; ++reg) {
            float grs = ar[reg] + fmaf(xv, wrs[reg], brs[reg]);
            float gzs = az[reg] + fmaf(xv, wzs[reg], bzs[reg]);
            float rg = __builtin_amdgcn_rcpf(1.f + __builtin_amdgcn_exp2f(grs));
            float zg = __builtin_amdgcn_rcpf(1.f + __builtin_amdgcn_exp2f(gzs));
            float gns = fmaf(rg, an[reg] + bnhs[reg], fmaf(xv, wns[reg], bnis[reg]));
            float tn = fmaf(-2.f, __builtin_amdgcn_rcpf(__builtin_amdgcn_exp2f(gns) + 1.f), 1.f);
            float hn = fmaf(zg, hprev[reg] - tn, tn);
            hprev[reg] = hn;
            hn4[reg] = hn;
        }
        uint2 uu;
        uu.x = pack_bf2(hn4[0], hn4[1]);
        uu.y = pack_bf2(hn4[2], hn4[3]);
        *(uint2*)(hbn + m * 136 + hcol0) = uu;
        if (t == tstar_m) {
            float4 hv; hv.x = hn4[0]; hv.y = hn4[1]; hv.z = hn4[2]; hv.w = hn4[3];
            *(float4*)embp = hv;
        }
        __syncthreads();
    }
}

// ============ MFMA matmul family ==========================================
// Block: 256 threads (4 waves), C-tile 32 rows x 128 cols, K=128 per chunk.
// A fp32 [M,K] -> bf16 LDS Abf[32][136]; W fp32 [K,N] -> bf16 LDS transposed
// Wt[128][136] (Wt[n][k]).  Frags (validated conventions from GRU kernels):
//   A-frag: lane holds A[m0 + (l&15)][kc*32 + q*8 + j]  -> D row = q*4+reg
//   B-frag: lane holds W[kc*32+q*8+j][n0 + (l&15)]      -> D col = l&15

// ---------------- multi-output matmul: C_o = act(A @ W_o + b_o) -----------
// K = 128.  N via param (W1: N=256, grid.y=2).  NW sequential W rounds.
template <int NW, int RELU>
__global__ __launch_bounds__(256) void mfma_mm_multi(
    const float* __restrict__ A, int N,
    const float* __restrict__ Wa, const float* __restrict__ ba, float* __restrict__ Ca,
    const float* __restrict__ Wb, const float* __restrict__ bb, float* __restrict__ Cb,
    const float* __restrict__ Wc, const float* __restrict__ bc, float* __restrict__ Cc)
{
    __shared__ __align__(16) unsigned short Abf[32][136];
    __shared__ __align__(16) unsigned short Wt[128][136];
    const int tid = threadIdx.x;
    const int row0 = blockIdx.x * 32;
    const int ncol0 = blockIdx.y * 128;
    const int w = tid >> 6, l = tid & 63, m16 = l & 15, q = l >> 4;

    // stage A (32 x 128) fp32 -> bf16
    for (int it = tid; it < 1024; it += 256) {
        int r = it >> 5, k4 = (it & 31) << 2;
        float4 a = *(const float4*)&A[(size_t)(row0 + r) * 128 + k4];
        uint2 p; p.x = pack_bf2(a.x, a.y); p.y = pack_bf2(a.z, a.w);
        *(uint2*)&Abf[r][k4] = p;
    }

    const float* Ws[3] = {Wa, Wb, Wc};
    const float* bs[3] = {ba, bb, bc};
    float* Cs[3] = {Ca, Cb, Cc};
    short8_t Af[2][4];

#pragma unroll
    for (int o = 0; o < NW; ++o) {
        __syncthreads();   // A ready (o=0) / Wt free to overwrite (o>0)
        const float* Wp = Ws[o];
        for (int it = tid; it < 4096; it += 256) {
            int n = it & 127, k4 = (it >> 7) << 2;
            int gn = ncol0 + n;
            float w0 = Wp[(size_t)(k4 + 0) * N + gn];
            float w1 = Wp[(size_t)(k4 + 1) * N + gn];
            float w2 = Wp[(size_t)(k4 + 2) * N + gn];
            float w3 = Wp[(size_t)(k4 + 3) * N + gn];
            uint2 p; p.x = pack_bf2(w0, w1); p.y = pack_bf2(w2, w3);
            *(uint2*)&Wt[n][k4] = p;
        }
        __syncthreads();
        if (o == 0) {
#pragma unroll
            for (int mt = 0; mt < 2; ++mt)
#pragma unroll
                for (int kc = 0; kc < 4; ++kc)
                    Af[mt][kc] = *(const short8_t*)&Abf[mt * 16 + m16][kc * 32 + q * 8];
        }
        short8_t Bf[2][4];
#pragma unroll
        for (int nt = 0; nt < 2; ++nt)
#pragma unroll
            for (int kc = 0; kc < 4; ++kc)
                Bf[nt][kc] = *(const short8_t*)&Wt[w * 32 + nt * 16 + m16][kc * 32 + q * 8];
        float4_t acc[2][2];
#pragma unroll
        for (int mt = 0; mt < 2; ++mt)
#pragma unroll
            for (int nt = 0; nt < 2; ++nt)
                acc[mt][nt] = (float4_t){0.f, 0.f, 0.f, 0.f};
#pragma unroll
        for (int kc = 0; kc < 4; ++kc)
#pragma unroll
            for (int mt = 0; mt < 2; ++mt)
#pragma unroll
                for (int nt = 0; nt < 2; ++nt)
                    acc[mt][nt] = __builtin_amdgcn_mfma_f32_16x16x32_bf16(
                        Af[mt][kc], Bf[nt][kc], acc[mt][nt], 0, 0, 0);
        const float* bp = bs[o];
        float* Cp = Cs[o];
#pragma unroll
        for (int nt = 0; nt < 2; ++nt) {
            int col = ncol0 + w * 32 + nt * 16 + m16;
            float bv = bp[col];
#pragma unroll
            for (int mt = 0; mt < 2; ++mt)
#pragma unroll
                for (int reg = 0; reg < 4; ++reg) {
                    float v = acc[mt][nt][reg] + bv;
                    if (RELU) v = fmaxf(v, 0.f);
                    Cp[(size_t)(row0 + mt * 16 + q * 4 + reg) * N + col] = v;
                }
        }
    }
}

// ---------------- matmul + bias + residual + LayerNorm, N=128 -------------
template <int K>
__global__ __launch_bounds__(256) void mfma_mm_ln(
    const float* __restrict__ A, const float* __restrict__ W,
    const float* __restrict__ bias, const float* __restrict__ res,
    const float* __restrict__ g, const float* __restrict__ be,
    float* __restrict__ C)
{
    __shared__ __align__(16) unsigned short Abf[32][136];
    __shared__ __align__(16) unsigned short Wt[128][136];
    __shared__ float v_s[32][129];
    const int tid = threadIdx.x;
    const int row0 = blockIdx.x * 32;
    const int w = tid >> 6, l = tid & 63, m16 = l & 15, q = l >> 4;

    float4_t acc[2][2];
#pragma unroll
    for (int mt = 0; mt < 2; ++mt)
#pragma unroll
        for (int nt = 0; nt < 2; ++nt)
            acc[mt][nt] = (float4_t){0.f, 0.f, 0.f, 0.f};

    for (int kb = 0; kb < K; kb += 128) {
        __syncthreads();
        for (int it = tid; it < 1024; it += 256) {
            int r = it >> 5, k4 = (it & 31) << 2;
            float4 a = *(const float4*)&A[(size_t)(row0 + r) * K + kb + k4];
            uint2 p; p.x = pack_bf2(a.x, a.y); p.y = pack_bf2(a.z, a.w);
            *(uint2*)&Abf[r][k4] = p;
        }
        for (int it = tid; it < 4096; it += 256) {
            int n = it & 127, k4 = (it >> 7) << 2;
            float w0 = W[(size_t)(kb + k4 + 0) * HH + n];
            float w1 = W[(size_t)(kb + k4 + 1) * HH + n];
            float w2 = W[(size_t)(kb + k4 + 2) * HH + n];
            float w3 = W[(size_t)(kb + k4 + 3) * HH + n];
            uint2 p; p.x = pack_bf2(w0, w1); p.y = pack_bf2(w2, w3);
            *(uint2*)&Wt[n][k4] = p;
        }
        __syncthreads();
        short8_t Af[2][4], Bf[2][4];
#pragma unroll
        for (int mt = 0; mt < 2; ++mt)
#pragma unroll
            for (int kc = 0; kc < 4; ++kc)
                Af[mt][kc] = *(const short8_t*)&Abf[mt * 16 + m16][kc * 32 + q * 8];
#pragma unroll
        for (int nt = 0; nt < 2; ++nt)
#pragma unroll
            for (int kc = 0; kc < 4; ++kc)
                Bf[nt][kc] = *(const short8_t*)&Wt[w * 32 + nt * 16 + m16][kc * 32 + q * 8];
#pragma unroll
        for (int kc = 0; kc < 4; ++kc)
#pragma unroll
            for (int mt = 0; mt < 2; ++mt)
#pragma unroll
                for (int nt = 0; nt < 2; ++nt)
                    acc[mt][nt] = __builtin_amdgcn_mfma_f32_16x16x32_bf16(
                        Af[mt][kc], Bf[nt][kc], acc[mt][nt], 0, 0, 0);
    }

    // epilogue: + bias + residual into LDS
#pragma unroll
    for (int nt = 0; nt < 2; ++nt) {
        int col = w * 32 + nt * 16 + m16;
        float bv = bias[col];
#pragma unroll
        for (int mt = 0; mt < 2; ++mt)
#pragma unroll
            for (int reg = 0; reg < 4; ++reg) {
                int row = mt * 16 + q * 4 + reg;
                v_s[row][col] = acc[mt][nt][reg] + bv +
                                res[(size_t)(row0 + row) * HH + col];
            }
    }
    __syncthreads();
    // LayerNorm: row = tid>>3, 8 lanes/row, cols js + 8c (conflict-free)
    int r2 = tid >> 3, js = tid & 7;
    float s = 0.f;
#pragma unroll
    for (int c = 0; c < 16; ++c) s += v_s[r2][js + 8 * c];
    s += __shfl_xor(s, 1); s += __shfl_xor(s, 2); s += __shfl_xor(s, 4);
    float mean = s * (1.f / 128.f);
    float vs = 0.f;
#pragma unroll
    for (int c = 0; c < 16; ++c) {
        float dv = v_s[r2][js + 8 * c] - mean;
        vs += dv * dv;
    }
    vs += __shfl_xor(vs, 1); vs += __shfl_xor(vs, 2); vs += __shfl_xor(vs, 4);
    float rs = rsqrtf(vs * (1.f / 128.f) + 1e-5f);
#pragma unroll
    for (int c = 0; c < 16; ++c) {
        int col = js + 8 * c;
        C[(size_t)(row0 + r2) * HH + col] =
            (v_s[r2][col] - mean) * rs * g[col] + be[col];
    }
}

// ---------------- MHA core: block (b, head), 256 threads ------------------
__global__ __launch_bounds__(256) void attn_kernel(
    const float* __restrict__ qb, const float* __restrict__ kb,
    const float* __restrict__ vb, float* __restrict__ ob)
{
    int b = blockIdx.x & (BB - 1), hd = blockIdx.x >> 7;
    int tid = threadIdx.x;
    int qrow = tid & 63, qq = tid >> 6;
    __shared__ float k_s[DD][32];
    __shared__ float v_s[DD][32];
    __shared__ float s_s[DD][65];
    __shared__ float mxp_s[DD][4];
    __shared__ float smp_s[DD][4];
    const float scale = 0.17677669529663687f;
    for (int idx = tid; idx < DD * 8; idx += 256) {
        int row = idx >> 3, c4 = (idx & 7) * 4;
        float4 kv = *(const float4*)&kb[((size_t)b * DD + row) * HH + hd * 32 + c4];
        float4 vv = *(const float4*)&vb[((size_t)b * DD + row) * HH + hd * 32 + c4];
        kv.x *= scale; kv.y *= scale; kv.z *= scale; kv.w *= scale;
        *(float4*)&k_s[row][c4] = kv;
        *(float4*)&v_s[row][c4] = vv;
    }
    float qv[32];
    const float* qp = qb + ((size_t)b * DD + qrow) * HH + hd * 32;
#pragma unroll
    for (int c4 = 0; c4 < 8; ++c4) {
        float4 t = *(const float4*)(qp + c4 * 4);
        qv[c4 * 4 + 0] = t.x; qv[c4 * 4 + 1] = t.y;
        qv[c4 * 4 + 2] = t.z; qv[c4 * 4 + 3] = t.w;
    }
    __syncthreads();
    float mx = -1e30f;
#pragma unroll
    for (int j0 = 0; j0 < 16; ++j0) {
        int j = qq * 16 + j0;
        float s = 0.f;
#pragma unroll
        for (int mm = 0; mm < 32; ++mm) s = fmaf(qv[mm], k_s[j][mm], s);
        s_s[qrow][j] = s;
        mx = fmaxf(mx, s);
    }
    mxp_s[qrow][qq] = mx;
    __syncthreads();
    float m4 = fmaxf(fmaxf(mxp_s[qrow][0], mxp_s[qrow][1]),
                     fmaxf(mxp_s[qrow][2], mxp_s[qrow][3]));
    float sum = 0.f;
#pragma unroll
    for (int j0 = 0; j0 < 16; ++j0) {
        int j = qq * 16 + j0;
        float p = __expf(s_s[qrow][j] - m4);
        s_s[qrow][j] = p;
        sum += p;
    }
    smp_s[qrow][qq] = sum;
    __syncthreads();
    float inv = __builtin_amdgcn_rcpf(smp_s[qrow][0] + smp_s[qrow][1] +
                                      smp_s[qrow][2] + smp_s[qrow][3]);
    float o[8];
#pragma unroll
    for (int c = 0; c < 8; ++c) o[c] = 0.f;
    for (int j = 0; j < DD; ++j) {
        float p = s_s[qrow][j];
#pragma unroll
        for (int c = 0; c < 8; ++c) o[c] = fmaf(p, v_s[j][qq * 8 + c], o[c]);
    }
    float* op = ob + ((size_t)b * DD + qrow) * HH + hd * 32 + qq * 8;
    float4 o0, o1;
    o0.x = o[0] * inv; o0.y = o[1] * inv; o0.z = o[2] * inv; o0.w = o[3] * inv;
    o1.x = o[4] * inv; o1.y = o[5] * inv; o1.z = o[6] * inv; o1.w = o[7] * inv;
    *(float4*)op = o0;
    *(float4*)(op + 4) = o1;
}

// -------- final: fq inline, e=tanh(fq+fk)@Fout, softmax, out=a@fv ---------
__global__ __launch_bounds__(256) void final_reduce_kernel(
    const float* __restrict__ h2, const float* __restrict__ Fq,
    const float* __restrict__ fbq,
    const float* __restrict__ fkb, const float* __restrict__ fvb,
    const float* __restrict__ Fout, const float* __restrict__ fbout,
    float* __restrict__ out)
{
    int b = blockIdx.x;
    int tid = threadIdx.x;
    __shared__ float hlast[HH], fq_s[HH], fo_s[HH], e_s[DD];
    __shared__ float red_s[256];
    if (tid < HH) {
        hlast[tid] = h2[((size_t)b * DD + DD - 1) * HH + tid];
        fo_s[tid] = Fout[tid];
    }
    __syncthreads();
    if (tid < HH) {
        float a = fbq[tid];
#pragma unroll 8
        for (int mm2 = 0; mm2 < HH; ++mm2)
            a = fmaf(hlast[mm2], Fq[mm2 * HH + tid], a);
        fq_s[tid] = a;
    }
    __syncthreads();
    int dd = tid >> 2, sub = tid & 3;
    const float* fkrow = fkb + ((size_t)b * DD + dd) * HH + sub * 32;
    float p = 0.f;
#pragma unroll 8
    for (int mm = 0; mm < 32; ++mm)
        p = fmaf(tanhf(fq_s[sub * 32 + mm] + fkrow[mm]), fo_s[sub * 32 + mm], p);
    p += __shfl_xor(p, 1);
    p += __shfl_xor(p, 2);
    if (sub == 0) e_s[dd] = p + fbout[0];
    __syncthreads();
    if (tid < 64) {
        float e = e_s[tid];
        float mx = e;
        for (int o = 32; o; o >>= 1) mx = fmaxf(mx, __shfl_xor(mx, o));
        float pe = __expf(e - mx);
        float s = pe;
        for (int o = 32; o; o >>= 1) s += __shfl_xor(s, o);
        e_s[tid] = pe / s;
    }
    __syncthreads();
    int col = tid & 127, rg = tid >> 7;
    float acc = 0.f;
    for (int d2 = rg * 32; d2 < rg * 32 + 32; ++d2)
        acc = fmaf(e_s[d2], fvb[((size_t)b * DD + d2) * HH + col], acc);
    red_s[tid] = acc;
    __syncthreads();
    if (rg == 0)
        out[(size_t)b * HH + col] = red_s[col] + red_s[col + 128];
}

// ---------------- launch ---------------------------------------------------
extern "C" void kernel_launch(void* const* d_in, const int* in_sizes, int n_in,
                              void* d_out, int out_size, void* d_ws, size_t ws_size,
                              hipStream_t stream)
{
    const float* x    = (const float*)d_in[0];
    const int*   mask = (const int*)d_in[1];
    const float* Wih  = (const float*)d_in[2];
    const float* Whh  = (const float*)d_in[3];
    const float* bih  = (const float*)d_in[4];
    const float* bhh  = (const float*)d_in[5];
    const float* Wq = (const float*)d_in[6];   const float* bq = (const float*)d_in[7];
    const float* Wk = (const float*)d_in[8];   const float* bk = (const float*)d_in[9];
    const float* Wv = (const float*)d_in[10];  const float* bv = (const float*)d_in[11];
    const float* Wo = (const float*)d_in[12];  const float* bo = (const float*)d_in[13];
    const float* W1 = (const float*)d_in[14];  const float* b1 = (const float*)d_in[15];
    const float* W2 = (const float*)d_in[16];  const float* b2 = (const float*)d_in[17];
    const float* g1 = (const float*)d_in[18];  const float* be1 = (const float*)d_in[19];
    const float* g2 = (const float*)d_in[20];  const float* be2 = (const float*)d_in[21];
    const float* Fq = (const float*)d_in[22];  const float* fbq = (const float*)d_in[23];
    const float* Fk = (const float*)d_in[24];  const float* fbk = (const float*)d_in[25];
    const float* Fv = (const float*)d_in[26];  const float* fbv = (const float*)d_in[27];
    const float* Fout = (const float*)d_in[28]; const float* fbout = (const float*)d_in[29];
    float* out = (float*)d_out;
    float* ws  = (float*)d_ws;

    float* emb = ws;                  // 1048576
    float* qb  = ws + 1048576;
    float* kb  = ws + 2097152;
    float* vb  = ws + 3145728;
    float* ob  = ws + 4194304;
    float* h1  = ws + 5242880;
    float* a1  = ws + 6291456;        // 2097152
    float* h2  = ws + 8388608;
    float* fkb = ws + 9437184;
    float* fvb = ws + 10485760;       // end 11534336 floats (~46 MB)

    gru_mfma_kernel<<<dim3(DD, BB / 16), 512, 0, stream>>>(x, mask, Wih, Whh, bih, bhh, emb);
    mfma_mm_multi<3, 0><<<dim3(256, 1), 256, 0, stream>>>(
        emb, HH, Wq, bq, qb, Wk, bk, kb, Wv, bv, vb);
    attn_kernel<<<BB * NHH, 256, 0, stream>>>(qb, kb, vb, ob);
    mfma_mm_ln<128><<<256, 256, 0, stream>>>(ob, Wo, bo, emb, g1, be1, h1);
    mfma_mm_multi<1, 1><<<dim3(256, 2), 256, 0, stream>>>(
        h1, 2 * HH, W1, b1, a1, nullptr, nullptr, nullptr, nullptr, nullptr, nullptr);
    mfma_mm_ln<256><<<256, 256, 0, stream>>>(a1, W2, b2, h1, g2, be2, h2);
    mfma_mm_multi<2, 0><<<dim3(256, 1), 256, 0, stream>>>(
        h2, HH, Fk, fbk, fkb, Fv, fbv, fvb, nullptr, nullptr, nullptr);
    final_reduce_kernel<<<BB, 256, 0, stream>>>(h2, Fq, fbq, fkb, fvb, Fout, fbout, out);
}

// Round 8
// 269.254 us; speedup vs baseline: 7.8340x; 1.0798x over previous
//
#include <hip/hip_runtime.h>
#include <math.h>

#define BB 128
#define TT 64
#define DD 64
#define HH 128
#define NHH 4
#define K3H 384        // 3*H

typedef __attribute__((ext_vector_type(8))) short short8_t;   // 8 bf16
typedef __attribute__((ext_vector_type(4))) float float4_t;

#define LOG2E 1.4426950408889634f

__device__ __forceinline__ unsigned short f2bf(float f) {
    unsigned int u = __float_as_uint(f);
    u += 0x7fffu + ((u >> 16) & 1u);      // RNE
    return (unsigned short)(u >> 16);
}

__device__ __forceinline__ unsigned pack_bf2(float lo, float hi) {
    return (unsigned)f2bf(lo) | ((unsigned)f2bf(hi) << 16);
}

__device__ __forceinline__ float bf2f(unsigned short s) {
    return __uint_as_float((unsigned)s << 16);
}

// ---------------- per-feature GRU via bf16 MFMA (unchanged, ~102 us) ------
__global__ __launch_bounds__(512, 4) void gru_mfma_kernel(
    const float* __restrict__ x, const int* __restrict__ mask,
    const float* __restrict__ Wih, const float* __restrict__ Whh,
    const float* __restrict__ bih, const float* __restrict__ bhh,
    float* __restrict__ emb)
{
    const int d  = blockIdx.x;
    const int b0 = blockIdx.y * 16;
    const int tid = threadIdx.x;
    const int w = tid >> 6;
    const int l = tid & 63;
    const int m = l & 15;
    const int q = l >> 4;

    __shared__ __align__(16) unsigned short hbuf[2][16][136];
    __shared__ float xs_t[TT][16];
    __shared__ int tstar_s[16];

    for (int idx = tid; idx < 16 * TT; idx += 512) {
        int t = idx >> 4, row = idx & 15;
        xs_t[t][row] = x[((size_t)(b0 + row) * TT + t) * DD + d];
    }
    if (tid < 16) {
        int b = b0 + tid, len = 0;
        for (int t = 0; t < TT; ++t) len += mask[b * TT + t];
        int ts = len - 1;
        if (ts < 0) ts = 0;
        if (ts > TT - 1) ts = TT - 1;
        tstar_s[tid] = ts;
    }
    for (int idx = tid; idx < 16 * 136; idx += 512)
        ((unsigned short*)hbuf)[idx] = 0;

    short8_t Wf[3][4];
#pragma unroll
    for (int g = 0; g < 3; ++g) {
        float sc = (g == 2) ? (2.f * LOG2E) : (-LOG2E);
        int kcol = g * HH + 16 * w + m;
        const float* wrow = Whh + ((size_t)d * K3H + kcol) * HH;
#pragma unroll
        for (int kc = 0; kc < 4; ++kc) {
            int j0 = kc * 32 + q * 8;
            float4 w0 = *(const float4*)(wrow + j0);
            float4 w1 = *(const float4*)(wrow + j0 + 4);
            short8_t f;
            f[0] = (short)f2bf(w0.x * sc); f[1] = (short)f2bf(w0.y * sc);
            f[2] = (short)f2bf(w0.z * sc); f[3] = (short)f2bf(w0.w * sc);
            f[4] = (short)f2bf(w1.x * sc); f[5] = (short)f2bf(w1.y * sc);
            f[6] = (short)f2bf(w1.z * sc); f[7] = (short)f2bf(w1.w * sc);
            Wf[g][kc] = f;
        }
    }

    const int hcol0 = 16 * w + q * 4;
    float4 wr4 = *(const float4*)&Wih[d * K3H + hcol0];
    float4 wz4 = *(const float4*)&Wih[d * K3H + HH + hcol0];
    float4 wn4 = *(const float4*)&Wih[d * K3H + 2 * HH + hcol0];
    float4 br4 = *(const float4*)&bih[d * K3H + hcol0];
    float4 bz4 = *(const float4*)&bih[d * K3H + HH + hcol0];
    float4 bni4 = *(const float4*)&bih[d * K3H + 2 * HH + hcol0];
    float4 bhr4 = *(const float4*)&bhh[d * K3H + hcol0];
    float4 bhz4 = *(const float4*)&bhh[d * K3H + HH + hcol0];
    float4 bnh4 = *(const float4*)&bhh[d * K3H + 2 * HH + hcol0];
    float brs[4], bzs[4], bnis[4], bnhs[4], wrs[4], wzs[4], wns[4];
#pragma unroll
    for (int r = 0; r < 4; ++r) {
        wrs[r] = -LOG2E * ((const float*)&wr4)[r];
        wzs[r] = -LOG2E * ((const float*)&wz4)[r];
        wns[r] = 2.f * LOG2E * ((const float*)&wn4)[r];
        brs[r] = -LOG2E * (((const float*)&br4)[r] + ((const float*)&bhr4)[r]);
        bzs[r] = -LOG2E * (((const float*)&bz4)[r] + ((const float*)&bhz4)[r]);
        bnis[r] = 2.f * LOG2E * ((const float*)&bni4)[r];
        bnhs[r] = 2.f * LOG2E * ((const float*)&bnh4)[r];
    }

    float hprev[4];
#pragma unroll
    for (int i = 0; i < 4; ++i) hprev[i] = 0.f;

    __syncthreads();
    const int tstar_m = tstar_s[m];
    float* embp = emb + (((size_t)(b0 + m)) * DD + d) * HH + hcol0;

    for (int t = 0; t < TT; ++t) {
        const unsigned short* hb = &hbuf[t & 1][0][0];
        unsigned short* hbn = &hbuf[(t & 1) ^ 1][0][0];

        short8_t hf[4];
#pragma unroll
        for (int kc = 0; kc < 4; ++kc)
            hf[kc] = *(const short8_t*)(hb + m * 136 + kc * 32 + q * 8);
        float xv = xs_t[t][m];

        float4_t ar = {0.f,0.f,0.f,0.f}, az = {0.f,0.f,0.f,0.f}, an = {0.f,0.f,0.f,0.f};
#pragma unroll
        for (int kc = 0; kc < 4; ++kc) {
            ar = __builtin_amdgcn_mfma_f32_16x16x32_bf16(Wf[0][kc], hf[kc], ar, 0, 0, 0);
            az = __builtin_amdgcn_mfma_f32_16x16x32_bf16(Wf[1][kc], hf[kc], az, 0, 0, 0);
            an = __builtin_amdgcn_mfma_f32_16x16x32_bf16(Wf[2][kc], hf[kc], an, 0, 0, 0);
        }

        float hn4[4];
#pragma unroll
        for (int reg = 0; reg < 4; ++reg) {
            float grs = ar[reg] + fmaf(xv, wrs[reg], brs[reg]);
            float gzs = az[reg] + fmaf(xv, wzs[reg], bzs[reg]);
            float rg = __builtin_amdgcn_rcpf(1.f + __builtin_amdgcn_exp2f(grs));
            float zg = __builtin_amdgcn_rcpf(1.f + __builtin_amdgcn_exp2f(gzs));
            float gns = fmaf(rg, an[reg] + bnhs[reg], fmaf(xv, wns[reg], bnis[reg]));
            float tn = fmaf(-2.f, __builtin_amdgcn_rcpf(__builtin_amdgcn_exp2f(gns) + 1.f), 1.f);
            float hn = fmaf(zg, hprev[reg] - tn, tn);
            hprev[reg] = hn;
            hn4[reg] = hn;
        }
        uint2 uu;
        uu.x = pack_bf2(hn4[0], hn4[1]);
        uu.y = pack_bf2(hn4[2], hn4[3]);
        *(uint2*)(hbn + m * 136 + hcol0) = uu;
        if (t == tstar_m) {
            float4 hv; hv.x = hn4[0]; hv.y = hn4[1]; hv.z = hn4[2]; hv.w = hn4[3];
            *(float4*)embp = hv;
        }
        __syncthreads();
    }
}

// ============ fused tail: one block per batch element =====================
// 512 threads (8 waves). Validated MFMA conventions (round 7):
//   A-frag: lane = S[mt*16 + (l&15)][kc*32 + q*8 + j]
//   B-frag: lane = Wt[n-col][k] with n-col = w*16 + (l&15)
//   C: row = mt*16 + q*4 + reg, col = w*16 + (l&15)

__device__ __forceinline__ void stage_w(unsigned short (*Wt)[136],
                                        const float* __restrict__ Wp,
                                        int Nst, int n0, float scale, int tid)
{
    for (int it = tid; it < 4096; it += 512) {
        int n = it & 127, k4 = (it >> 7) << 2;
        const float* p = Wp + (size_t)k4 * Nst + n0 + n;
        float w0 = p[0], w1 = p[Nst], w2 = p[2 * Nst], w3 = p[3 * Nst];
        uint2 pk;
        pk.x = pack_bf2(w0 * scale, w1 * scale);
        pk.y = pack_bf2(w2 * scale, w3 * scale);
        *(uint2*)&Wt[n][k4] = pk;
    }
}

__device__ __forceinline__ void load_afrag(const unsigned short (*S)[136],
                                           short8_t Af[4][4], int m16, int q)
{
#pragma unroll
    for (int mt = 0; mt < 4; ++mt)
#pragma unroll
        for (int kc = 0; kc < 4; ++kc)
            Af[mt][kc] = *(const short8_t*)&S[mt * 16 + m16][kc * 32 + q * 8];
}

__device__ __forceinline__ void mm_acc(const unsigned short (*Wt)[136],
                                       short8_t Af[4][4], float4_t acc[4],
                                       int w, int m16, int q)
{
    short8_t Bf[4];
#pragma unroll
    for (int kc = 0; kc < 4; ++kc)
        Bf[kc] = *(const short8_t*)&Wt[w * 16 + m16][kc * 32 + q * 8];
#pragma unroll
    for (int mt = 0; mt < 4; ++mt) {
        float4_t a = acc[mt];
#pragma unroll
        for (int kc = 0; kc < 4; ++kc)
            a = __builtin_amdgcn_mfma_f32_16x16x32_bf16(Af[mt][kc], Bf[kc], a, 0, 0, 0);
        acc[mt] = a;
    }
}

__device__ __forceinline__ void zero4(float4_t acc[4]) {
#pragma unroll
    for (int mt = 0; mt < 4; ++mt) acc[mt] = (float4_t){0.f, 0.f, 0.f, 0.f};
}

__device__ __forceinline__ void store_bf(unsigned short (*Dst)[136], float4_t acc[4],
                                         const float* __restrict__ bias, int n0,
                                         float bscale, int relu,
                                         int w, int m16, int q)
{
    float bv = bias[n0 + w * 16 + m16] * bscale;
#pragma unroll
    for (int mt = 0; mt < 4; ++mt)
#pragma unroll
        for (int reg = 0; reg < 4; ++reg) {
            float v = acc[mt][reg] + bv;
            if (relu) v = fmaxf(v, 0.f);
            Dst[mt * 16 + q * 4 + reg][w * 16 + m16] = f2bf(v);
        }
}

__global__ __launch_bounds__(512) void tail_kernel(
    const float* __restrict__ emb,
    const float* __restrict__ Wq, const float* __restrict__ bq,
    const float* __restrict__ Wk, const float* __restrict__ bk,
    const float* __restrict__ Wv, const float* __restrict__ bv,
    const float* __restrict__ Wo, const float* __restrict__ bo,
    const float* __restrict__ W1, const float* __restrict__ b1,
    const float* __restrict__ W2, const float* __restrict__ b2,
    const float* __restrict__ g1, const float* __restrict__ be1,
    const float* __restrict__ g2, const float* __restrict__ be2,
    const float* __restrict__ Fq, const float* __restrict__ fbq,
    const float* __restrict__ Fk, const float* __restrict__ fbk,
    const float* __restrict__ Fv, const float* __restrict__ fbv,
    const float* __restrict__ Fout, const float* __restrict__ fbout,
    float* __restrict__ h1g, float* __restrict__ out)
{
    const int b = blockIdx.x;
    const int tid = threadIdx.x;
    const int w = tid >> 6, l = tid & 63, m16 = l & 15, q = l >> 4;
    const int col = w * 16 + m16;

    __shared__ __align__(16) unsigned short E[64][136];   // emb -> o -> h1 -> h2
    __shared__ __align__(16) unsigned short Qs[64][136];  // q -> a1_lo -> fk
    __shared__ __align__(16) unsigned short Ks[64][136];  // k -> a1_hi -> fv
    __shared__ __align__(16) unsigned short Vs[64][136];  // v
    __shared__ __align__(16) unsigned short Wt[128][136]; // staged weight
    __shared__ float sc[64][66];
    __shared__ float lnp[64][8], lnp2[64][8];
    __shared__ float inv_s[64], mean_s[64], rs_s[64];
    __shared__ float fq_s[128], fo_s[128], e_s[64], red_s[256];

    const float* embB = emb + (size_t)b * 64 * 128;
    float* h1gB = h1g + (size_t)b * 64 * 128;
    const float SS = 0.17677669529663687f;   // 1/sqrt(32) folded into q

    // ---- stage emb (fp32 -> bf16) + prefetch Wq ----
    for (int it = tid; it < 2048; it += 512) {
        int r = it >> 5, c4 = (it & 31) << 2;
        float4 a = *(const float4*)&embB[r * 128 + c4];
        uint2 p; p.x = pack_bf2(a.x, a.y); p.y = pack_bf2(a.z, a.w);
        *(uint2*)&E[r][c4] = p;
    }
    stage_w(Wt, Wq, 128, 0, SS, tid);
    __syncthreads();

    short8_t AfE[4][4];
    float4_t acc[4];
    load_afrag(E, AfE, m16, q);

    // ---- QKV ----
    zero4(acc); mm_acc(Wt, AfE, acc, w, m16, q);
    store_bf(Qs, acc, bq, 0, SS, 0, w, m16, q);
    __syncthreads();
    stage_w(Wt, Wk, 128, 0, 1.f, tid);
    __syncthreads();
    zero4(acc); mm_acc(Wt, AfE, acc, w, m16, q);
    store_bf(Ks, acc, bk, 0, 1.f, 0, w, m16, q);
    __syncthreads();
    stage_w(Wt, Wv, 128, 0, 1.f, tid);
    __syncthreads();
    zero4(acc); mm_acc(Wt, AfE, acc, w, m16, q);
    store_bf(Vs, acc, bv, 0, 1.f, 0, w, m16, q);
    __syncthreads();

    // ---- attention (4 heads, dk=32) ----
    for (int hd = 0; hd < 4; ++hd) {
        {   // scores via MFMA: wave w -> mt = w>>1, nt = (w&1)*2 + {0,1}
            int mt = w >> 1;
            short8_t Aq = *(const short8_t*)&Qs[mt * 16 + m16][hd * 32 + q * 8];
#pragma unroll
            for (int nn = 0; nn < 2; ++nn) {
                int nt = (w & 1) * 2 + nn;
                short8_t Bk = *(const short8_t*)&Ks[nt * 16 + m16][hd * 32 + q * 8];
                float4_t a = {0.f, 0.f, 0.f, 0.f};
                a = __builtin_amdgcn_mfma_f32_16x16x32_bf16(Aq, Bk, a, 0, 0, 0);
#pragma unroll
                for (int reg = 0; reg < 4; ++reg)
                    sc[mt * 16 + q * 4 + reg][nt * 16 + m16] = a[reg];
            }
        }
        __syncthreads();
        {   // softmax: row = tid>>3, 8 threads/row
            int row = tid >> 3, c8 = tid & 7;
            float vals[8]; float mx = -1e30f;
#pragma unroll
            for (int c = 0; c < 8; ++c) { vals[c] = sc[row][c8 + 8 * c]; mx = fmaxf(mx, vals[c]); }
            mx = fmaxf(mx, __shfl_xor(mx, 1));
            mx = fmaxf(mx, __shfl_xor(mx, 2));
            mx = fmaxf(mx, __shfl_xor(mx, 4));
            float sum = 0.f;
#pragma unroll
            for (int c = 0; c < 8; ++c) {
                float p = __expf(vals[c] - mx);
                sc[row][c8 + 8 * c] = p;
                sum += p;
            }
            sum += __shfl_xor(sum, 1); sum += __shfl_xor(sum, 2); sum += __shfl_xor(sum, 4);
            if (c8 == 0) inv_s[row] = __builtin_amdgcn_rcpf(sum);
        }
        __syncthreads();
        {   // PV (VALU fp32): qrow = l, wave w handles 4 cols; o -> E
            float o0 = 0.f, o1 = 0.f, o2 = 0.f, o3 = 0.f;
            for (int j = 0; j < 64; ++j) {
                float p = sc[l][j];
                uint2 vv = *(const uint2*)&Vs[j][hd * 32 + w * 4];
                o0 = fmaf(p, __uint_as_float(vv.x << 16), o0);
                o1 = fmaf(p, __uint_as_float(vv.x & 0xffff0000u), o1);
                o2 = fmaf(p, __uint_as_float(vv.y << 16), o2);
                o3 = fmaf(p, __uint_as_float(vv.y & 0xffff0000u), o3);
            }
            float iv = inv_s[l];
            uint2 pk; pk.x = pack_bf2(o0 * iv, o1 * iv); pk.y = pack_bf2(o2 * iv, o3 * iv);
            *(uint2*)&E[l][hd * 32 + w * 4] = pk;
        }
        __syncthreads();
    }

    // ---- Wo + residual(emb fp32) + LN1 -> E (h1 bf16), h1g (fp32) ----
    stage_w(Wt, Wo, 128, 0, 1.f, tid);
    __syncthreads();
    short8_t AfX[4][4];
    load_afrag(E, AfX, m16, q);
    zero4(acc); mm_acc(Wt, AfX, acc, w, m16, q);
    float vals[4][4];
    {
        float bv = bo[col];
#pragma unroll
        for (int mt = 0; mt < 4; ++mt)
#pragma unroll
            for (int reg = 0; reg < 4; ++reg) {
                int row = mt * 16 + q * 4 + reg;
                vals[mt][reg] = acc[mt][reg] + bv + embB[row * 128 + col];
            }
    }
    // LN reduction (sum & sumsq over 16-lane groups -> per-wave partials)
#pragma unroll
    for (int mt = 0; mt < 4; ++mt)
#pragma unroll
        for (int reg = 0; reg < 4; ++reg) {
            float s = vals[mt][reg], s2 = s * s;
            s += __shfl_xor(s, 1); s += __shfl_xor(s, 2); s += __shfl_xor(s, 4); s += __shfl_xor(s, 8);
            s2 += __shfl_xor(s2, 1); s2 += __shfl_xor(s2, 2); s2 += __shfl_xor(s2, 4); s2 += __shfl_xor(s2, 8);
            if (m16 == 0) { int row = mt * 16 + q * 4 + reg; lnp[row][w] = s; lnp2[row][w] = s2; }
        }
    __syncthreads();
    if (tid < 64) {
        float s = 0.f, s2 = 0.f;
#pragma unroll
        for (int k = 0; k < 8; ++k) { s += lnp[tid][k]; s2 += lnp2[tid][k]; }
        float mn = s * (1.f / 128.f);
        float var = s2 * (1.f / 128.f) - mn * mn;
        mean_s[tid] = mn;
        rs_s[tid] = rsqrtf(var + 1e-5f);
    }
    __syncthreads();
    {
        float gv = g1[col], bev = be1[col];
#pragma unroll
        for (int mt = 0; mt < 4; ++mt)
#pragma unroll
            for (int reg = 0; reg < 4; ++reg) {
                int row = mt * 16 + q * 4 + reg;
                float hv = (vals[mt][reg] - mean_s[row]) * rs_s[row] * gv + bev;
                E[row][col] = f2bf(hv);
                h1gB[(size_t)row * 128 + col] = hv;
            }
    }

    // ---- FFN1: a1 = relu(h1 @ W1 + b1), N=256 in two passes ----
    stage_w(Wt, W1, 256, 0, 1.f, tid);
    __syncthreads();                      // also covers E(h1) writes
    load_afrag(E, AfX, m16, q);
    zero4(acc); mm_acc(Wt, AfX, acc, w, m16, q);
    store_bf(Qs, acc, b1, 0, 1.f, 1, w, m16, q);
    __syncthreads();
    stage_w(Wt, W1, 256, 128, 1.f, tid);
    __syncthreads();
    zero4(acc); mm_acc(Wt, AfX, acc, w, m16, q);
    store_bf(Ks, acc, b1, 128, 1.f, 1, w, m16, q);
    __syncthreads();

    // ---- FFN2: h2 = LN2(a1 @ W2 + b2 + h1), K=256 in two chunks ----
    stage_w(Wt, W2, 128, 0, 1.f, tid);
    __syncthreads();
    short8_t AfY[4][4];
    load_afrag(Qs, AfY, m16, q);
    zero4(acc); mm_acc(Wt, AfY, acc, w, m16, q);
    __syncthreads();
    stage_w(Wt, W2 + (size_t)128 * 128, 128, 0, 1.f, tid);
    __syncthreads();
    load_afrag(Ks, AfY, m16, q);
    mm_acc(Wt, AfY, acc, w, m16, q);      // accumulate
    {
        float bv = b2[col];
#pragma unroll
        for (int mt = 0; mt < 4; ++mt)
#pragma unroll
            for (int reg = 0; reg < 4; ++reg) {
                int row = mt * 16 + q * 4 + reg;
                vals[mt][reg] = acc[mt][reg] + bv + h1gB[(size_t)row * 128 + col];
            }
    }
#pragma unroll
    for (int mt = 0; mt < 4; ++mt)
#pragma unroll
        for (int reg = 0; reg < 4; ++reg) {
            float s = vals[mt][reg], s2 = s * s;
            s += __shfl_xor(s, 1); s += __shfl_xor(s, 2); s += __shfl_xor(s, 4); s += __shfl_xor(s, 8);
            s2 += __shfl_xor(s2, 1); s2 += __shfl_xor(s2, 2); s2 += __shfl_xor(s2, 4); s2 += __shfl_xor(s2, 8);
            if (m16 == 0) { int row = mt * 16 + q * 4 + reg; lnp[row][w] = s; lnp2[row][w] = s2; }
        }
    __syncthreads();
    if (tid < 64) {
        float s = 0.f, s2 = 0.f;
#pragma unroll
        for (int k = 0; k < 8; ++k) { s += lnp[tid][k]; s2 += lnp2[tid][k]; }
        float mn = s * (1.f / 128.f);
        float var = s2 * (1.f / 128.f) - mn * mn;
        mean_s[tid] = mn;
        rs_s[tid] = rsqrtf(var + 1e-5f);
    }
    __syncthreads();
    {
        float gv = g2[col], bev = be2[col];
#pragma unroll
        for (int mt = 0; mt < 4; ++mt)
#pragma unroll
            for (int reg = 0; reg < 4; ++reg) {
                int row = mt * 16 + q * 4 + reg;
                float hv = (vals[mt][reg] - mean_s[row]) * rs_s[row] * gv + bev;
                E[row][col] = f2bf(hv);   // h2
            }
    }

    // ---- final attention: fk -> Qs, fv -> Ks, fq via VALU ----
    stage_w(Wt, Fk, 128, 0, 1.f, tid);
    __syncthreads();                      // covers E(h2) writes
    load_afrag(E, AfX, m16, q);
    zero4(acc); mm_acc(Wt, AfX, acc, w, m16, q);
    store_bf(Qs, acc, fbk, 0, 1.f, 0, w, m16, q);
    __syncthreads();
    stage_w(Wt, Fv, 128, 0, 1.f, tid);
    if (tid < 128) fo_s[tid] = Fout[tid];
    __syncthreads();
    zero4(acc); mm_acc(Wt, AfX, acc, w, m16, q);
    store_bf(Ks, acc, fbv, 0, 1.f, 0, w, m16, q);
    __syncthreads();

    if (tid < 128) {   // fq[t] = h2[last] . Fq[:,t] + fbq
        float a = fbq[tid];
        for (int mm2 = 0; mm2 < 128; ++mm2)
            a = fmaf(bf2f(E[63][mm2]), Fq[mm2 * 128 + tid], a);
        fq_s[tid] = a;
    }
    __syncthreads();
    {   // e[dd] = tanh(fq + fk[dd]) . Fout + fbout
        int dd = tid >> 3, c8 = tid & 7;
        float p = 0.f;
#pragma unroll
        for (int c = 0; c < 16; ++c) {
            int cc = c8 * 16 + c;
            float t = fq_s[cc] + bf2f(Qs[dd][cc]);
            float tn = 1.f - 2.f * __builtin_amdgcn_rcpf(
                __builtin_amdgcn_exp2f(2.f * LOG2E * t) + 1.f);
            p = fmaf(tn, fo_s[cc], p);
        }
        p += __shfl_xor(p, 1); p += __shfl_xor(p, 2); p += __shfl_xor(p, 4);
        if (c8 == 0) e_s[dd] = p + fbout[0];
    }
    __syncthreads();
    if (tid < 64) {   // softmax over D=64
        float e = e_s[tid], mx = e;
        for (int o = 32; o; o >>= 1) mx = fmaxf(mx, __shfl_xor(mx, o));
        float pe = __expf(e - mx);
        float s = pe;
        for (int o = 32; o; o >>= 1) s += __shfl_xor(s, o);
        e_s[tid] = pe / s;
    }
    __syncthreads();
    if (tid < 256) {  // out = a . fv
        int c2 = tid & 127, rg2 = tid >> 7;
        float a = 0.f;
        for (int d2 = rg2 * 32; d2 < rg2 * 32 + 32; ++d2)
            a = fmaf(e_s[d2], bf2f(Ks[d2][c2]), a);
        red_s[tid] = a;
    }
    __syncthreads();
    if (tid < 128)
        out[(size_t)b * 128 + tid] = red_s[tid] + red_s[tid + 128];
}

// ---------------- launch ---------------------------------------------------
extern "C" void kernel_launch(void* const* d_in, const int* in_sizes, int n_in,
                              void* d_out, int out_size, void* d_ws, size_t ws_size,
                              hipStream_t stream)
{
    const float* x    = (const float*)d_in[0];
    const int*   mask = (const int*)d_in[1];
    const float* Wih  = (const float*)d_in[2];
    const float* Whh  = (const float*)d_in[3];
    const float* bih  = (const float*)d_in[4];
    const float* bhh  = (const float*)d_in[5];
    const float* Wq = (const float*)d_in[6];   const float* bq = (const float*)d_in[7];
    const float* Wk = (const float*)d_in[8];   const float* bk = (const float*)d_in[9];
    const float* Wv = (const float*)d_in[10];  const float* bv = (const float*)d_in[11];
    const float* Wo = (const float*)d_in[12];  const float* bo = (const float*)d_in[13];
    const float* W1 = (const float*)d_in[14];  const float* b1 = (const float*)d_in[15];
    const float* W2 = (const float*)d_in[16];  const float* b2 = (const float*)d_in[17];
    const float* g1 = (const float*)d_in[18];  const float* be1 = (const float*)d_in[19];
    const float* g2 = (const float*)d_in[20];  const float* be2 = (const float*)d_in[21];
    const float* Fq = (const float*)d_in[22];  const float* fbq = (const float*)d_in[23];
    const float* Fk = (const float*)d_in[24];  const float* fbk = (const float*)d_in[25];
    const float* Fv = (const float*)d_in[26];  const float* fbv = (const float*)d_in[27];
    const float* Fout = (const float*)d_in[28]; const float* fbout = (const float*)d_in[29];
    float* out = (float*)d_out;
    float* ws  = (float*)d_ws;

    float* emb = ws;                  // 1048576 floats
    float* h1g = ws + 1048576;        // 1048576 floats

    gru_mfma_kernel<<<dim3(DD, BB / 16), 512, 0, stream>>>(x, mask, Wih, Whh, bih, bhh, emb);
    tail_kernel<<<BB, 512, 0, stream>>>(
        emb, Wq, bq, Wk, bk, Wv, bv, Wo, bo, W1, b1, W2, b2,
        g1, be1, g2, be2, Fq, fbq, Fk, fbk, Fv, fbv, Fout, fbout,
        h1g, out);
}

// Round 9
// 250.916 us; speedup vs baseline: 8.4066x; 1.0731x over previous
//
#include <hip/hip_runtime.h>
#include <math.h>

#define BB 128
#define TT 64
#define DD 64
#define HH 128
#define NHH 4
#define K3H 384        // 3*H

typedef __attribute__((ext_vector_type(8))) short short8_t;   // 8 bf16
typedef __attribute__((ext_vector_type(4))) float float4_t;

#define LOG2E 1.4426950408889634f

__device__ __forceinline__ unsigned short f2bf(float f) {
    unsigned int u = __float_as_uint(f);
    u += 0x7fffu + ((u >> 16) & 1u);      // RNE
    return (unsigned short)(u >> 16);
}

__device__ __forceinline__ unsigned pack_bf2(float lo, float hi) {
    return (unsigned)f2bf(lo) | ((unsigned)f2bf(hi) << 16);
}

__device__ __forceinline__ float bf2f(unsigned short s) {
    return __uint_as_float((unsigned)s << 16);
}

// ---------------- per-feature GRU via bf16 MFMA (unchanged, ~102 us) ------
__global__ __launch_bounds__(512, 4) void gru_mfma_kernel(
    const float* __restrict__ x, const int* __restrict__ mask,
    const float* __restrict__ Wih, const float* __restrict__ Whh,
    const float* __restrict__ bih, const float* __restrict__ bhh,
    float* __restrict__ emb)
{
    const int d  = blockIdx.x;
    const int b0 = blockIdx.y * 16;
    const int tid = threadIdx.x;
    const int w = tid >> 6;
    const int l = tid & 63;
    const int m = l & 15;
    const int q = l >> 4;

    __shared__ __align__(16) unsigned short hbuf[2][16][136];
    __shared__ float xs_t[TT][16];
    __shared__ int tstar_s[16];

    for (int idx = tid; idx < 16 * TT; idx += 512) {
        int t = idx >> 4, row = idx & 15;
        xs_t[t][row] = x[((size_t)(b0 + row) * TT + t) * DD + d];
    }
    if (tid < 16) {
        int b = b0 + tid, len = 0;
        for (int t = 0; t < TT; ++t) len += mask[b * TT + t];
        int ts = len - 1;
        if (ts < 0) ts = 0;
        if (ts > TT - 1) ts = TT - 1;
        tstar_s[tid] = ts;
    }
    for (int idx = tid; idx < 16 * 136; idx += 512)
        ((unsigned short*)hbuf)[idx] = 0;

    short8_t Wf[3][4];
#pragma unroll
    for (int g = 0; g < 3; ++g) {
        float sc = (g == 2) ? (2.f * LOG2E) : (-LOG2E);
        int kcol = g * HH + 16 * w + m;
        const float* wrow = Whh + ((size_t)d * K3H + kcol) * HH;
#pragma unroll
        for (int kc = 0; kc < 4; ++kc) {
            int j0 = kc * 32 + q * 8;
            float4 w0 = *(const float4*)(wrow + j0);
            float4 w1 = *(const float4*)(wrow + j0 + 4);
            short8_t f;
            f[0] = (short)f2bf(w0.x * sc); f[1] = (short)f2bf(w0.y * sc);
            f[2] = (short)f2bf(w0.z * sc); f[3] = (short)f2bf(w0.w * sc);
            f[4] = (short)f2bf(w1.x * sc); f[5] = (short)f2bf(w1.y * sc);
            f[6] = (short)f2bf(w1.z * sc); f[7] = (short)f2bf(w1.w * sc);
            Wf[g][kc] = f;
        }
    }

    const int hcol0 = 16 * w + q * 4;
    float4 wr4 = *(const float4*)&Wih[d * K3H + hcol0];
    float4 wz4 = *(const float4*)&Wih[d * K3H + HH + hcol0];
    float4 wn4 = *(const float4*)&Wih[d * K3H + 2 * HH + hcol0];
    float4 br4 = *(const float4*)&bih[d * K3H + hcol0];
    float4 bz4 = *(const float4*)&bih[d * K3H + HH + hcol0];
    float4 bni4 = *(const float4*)&bih[d * K3H + 2 * HH + hcol0];
    float4 bhr4 = *(const float4*)&bhh[d * K3H + hcol0];
    float4 bhz4 = *(const float4*)&bhh[d * K3H + HH + hcol0];
    float4 bnh4 = *(const float4*)&bhh[d * K3H + 2 * HH + hcol0];
    float brs[4], bzs[4], bnis[4], bnhs[4], wrs[4], wzs[4], wns[4];
#pragma unroll
    for (int r = 0; r < 4; ++r) {
        wrs[r] = -LOG2E * ((const float*)&wr4)[r];
        wzs[r] = -LOG2E * ((const float*)&wz4)[r];
        wns[r] = 2.f * LOG2E * ((const float*)&wn4)[r];
        brs[r] = -LOG2E * (((const float*)&br4)[r] + ((const float*)&bhr4)[r]);
        bzs[r] = -LOG2E * (((const float*)&bz4)[r] + ((const float*)&bhz4)[r]);
        bnis[r] = 2.f * LOG2E * ((const float*)&bni4)[r];
        bnhs[r] = 2.f * LOG2E * ((const float*)&bnh4)[r];
    }

    float hprev[4];
#pragma unroll
    for (int i = 0; i < 4; ++i) hprev[i] = 0.f;

    __syncthreads();
    const int tstar_m = tstar_s[m];
    float* embp = emb + (((size_t)(b0 + m)) * DD + d) * HH + hcol0;

    for (int t = 0; t < TT; ++t) {
        const unsigned short* hb = &hbuf[t & 1][0][0];
        unsigned short* hbn = &hbuf[(t & 1) ^ 1][0][0];

        short8_t hf[4];
#pragma unroll
        for (int kc = 0; kc < 4; ++kc)
            hf[kc] = *(const short8_t*)(hb + m * 136 + kc * 32 + q * 8);
        float xv = xs_t[t][m];

        float4_t ar = {0.f,0.f,0.f,0.f}, az = {0.f,0.f,0.f,0.f}, an = {0.f,0.f,0.f,0.f};
#pragma unroll
        for (int kc = 0; kc < 4; ++kc) {
            ar = __builtin_amdgcn_mfma_f32_16x16x32_bf16(Wf[0][kc], hf[kc], ar, 0, 0, 0);
            az = __builtin_amdgcn_mfma_f32_16x16x32_bf16(Wf[1][kc], hf[kc], az, 0, 0, 0);
            an = __builtin_amdgcn_mfma_f32_16x16x32_bf16(Wf[2][kc], hf[kc], an, 0, 0, 0);
        }

        float hn4[4];
#pragma unroll
        for (int reg = 0; reg < 4; ++reg) {
            float grs = ar[reg] + fmaf(xv, wrs[reg], brs[reg]);
            float gzs = az[reg] + fmaf(xv, wzs[reg], bzs[reg]);
            float rg = __builtin_amdgcn_rcpf(1.f + __builtin_amdgcn_exp2f(grs));
            float zg = __builtin_amdgcn_rcpf(1.f + __builtin_amdgcn_exp2f(gzs));
            float gns = fmaf(rg, an[reg] + bnhs[reg], fmaf(xv, wns[reg], bnis[reg]));
            float tn = fmaf(-2.f, __builtin_amdgcn_rcpf(__builtin_amdgcn_exp2f(gns) + 1.f), 1.f);
            float hn = fmaf(zg, hprev[reg] - tn, tn);
            hprev[reg] = hn;
            hn4[reg] = hn;
        }
        uint2 uu;
        uu.x = pack_bf2(hn4[0], hn4[1]);
        uu.y = pack_bf2(hn4[2], hn4[3]);
        *(uint2*)(hbn + m * 136 + hcol0) = uu;
        if (t == tstar_m) {
            float4 hv; hv.x = hn4[0]; hv.y = hn4[1]; hv.z = hn4[2]; hv.w = hn4[3];
            *(float4*)embp = hv;
        }
        __syncthreads();
    }
}

// ============ fused tail v2: register-resident weights ====================
// 512 threads (8 waves); wave w owns output cols [16w,16w+16).
//   A-frag: lane = S[mt*16 + (l&15)][kc*32 + q*8 + j]
//   B-frag (regs): lane = W[kc*32+q*8+j][16w + (l&15)]
//   C: row = mt*16 + q*4 + reg, col = 16w + (l&15)

__device__ __forceinline__ void load_wfrag(const float* __restrict__ Wp, int N,
                                           int col, float scale, int q,
                                           short8_t fr[4])
{
#pragma unroll
    for (int kc = 0; kc < 4; ++kc) {
        const float* p = Wp + (size_t)(kc * 32 + q * 8) * N + col;
        short8_t f;
#pragma unroll
        for (int j = 0; j < 8; ++j)
            f[j] = (short)f2bf(p[(size_t)j * N] * scale);
        fr[kc] = f;
    }
}

__device__ __forceinline__ void load_afrag(const unsigned short (*S)[136],
                                           short8_t Af[4][4], int m16, int q)
{
#pragma unroll
    for (int mt = 0; mt < 4; ++mt)
#pragma unroll
        for (int kc = 0; kc < 4; ++kc)
            Af[mt][kc] = *(const short8_t*)&S[mt * 16 + m16][kc * 32 + q * 8];
}

__device__ __forceinline__ void mm_regw(short8_t Af[4][4], short8_t Bf[4],
                                        float4_t acc[4])
{
#pragma unroll
    for (int mt = 0; mt < 4; ++mt) {
        float4_t a = acc[mt];
#pragma unroll
        for (int kc = 0; kc < 4; ++kc)
            a = __builtin_amdgcn_mfma_f32_16x16x32_bf16(Af[mt][kc], Bf[kc], a, 0, 0, 0);
        acc[mt] = a;
    }
}

__device__ __forceinline__ void zero4(float4_t acc[4]) {
#pragma unroll
    for (int mt = 0; mt < 4; ++mt) acc[mt] = (float4_t){0.f, 0.f, 0.f, 0.f};
}

__device__ __forceinline__ void store_rows(unsigned short (*Dst)[136], float4_t acc[4],
                                           float bv, int relu, int col, int q)
{
#pragma unroll
    for (int mt = 0; mt < 4; ++mt)
#pragma unroll
        for (int reg = 0; reg < 4; ++reg) {
            float v = acc[mt][reg] + bv;
            if (relu) v = fmaxf(v, 0.f);
            Dst[mt * 16 + q * 4 + reg][col] = f2bf(v);
        }
}

__global__ __launch_bounds__(512) void tail_kernel(
    const float* __restrict__ emb,
    const float* __restrict__ Wq, const float* __restrict__ bq,
    const float* __restrict__ Wk, const float* __restrict__ bk,
    const float* __restrict__ Wv, const float* __restrict__ bv,
    const float* __restrict__ Wo, const float* __restrict__ bo,
    const float* __restrict__ W1, const float* __restrict__ b1,
    const float* __restrict__ W2, const float* __restrict__ b2,
    const float* __restrict__ g1, const float* __restrict__ be1,
    const float* __restrict__ g2, const float* __restrict__ be2,
    const float* __restrict__ Fq, const float* __restrict__ fbq,
    const float* __restrict__ Fk, const float* __restrict__ fbk,
    const float* __restrict__ Fv, const float* __restrict__ fbv,
    const float* __restrict__ Fout, const float* __restrict__ fbout,
    float* __restrict__ out)
{
    const int b = blockIdx.x;
    const int tid = threadIdx.x;
    const int w = tid >> 6, l = tid & 63, m16 = l & 15, q = l >> 4;
    const int col = w * 16 + m16;

    __shared__ __align__(16) unsigned short E[64][136];   // emb->o->h1->h2
    __shared__ __align__(16) unsigned short Qs[64][136];  // q->P01->a1lo->fk
    __shared__ __align__(16) unsigned short Ks[64][136];  // k->P23->a1hi->fv
    __shared__ __align__(16) unsigned short Vt[128][72];  // V transposed
    __shared__ float sc4[4][64][66];                      // scores, 4 heads
    __shared__ float lnp[64][8], lnp2[64][8];
    __shared__ float mean_s[64], rs_s[64];
    __shared__ float fq_s[128], fo_s[128], e_s[64], red_s[256];

    const float* embB = emb + (size_t)b * 64 * 128;
    const float SS = 0.17677669529663687f;   // 1/sqrt(32)

    // ---- prefetch QKV weight frags + biases (covers emb staging) ----
    short8_t WqF[4], WkF[4], WvF[4];
    load_wfrag(Wq, 128, col, SS, q, WqF);
    load_wfrag(Wk, 128, col, 1.f, q, WkF);
    load_wfrag(Wv, 128, col, 1.f, q, WvF);
    float bqv = bq[col] * SS, bkv = bk[col], bvv = bv[col];

    // ---- stage emb fp32 -> bf16 ----
    for (int it = tid; it < 2048; it += 512) {
        int r = it >> 5, c4 = (it & 31) << 2;
        float4 a = *(const float4*)&embB[r * 128 + c4];
        uint2 p; p.x = pack_bf2(a.x, a.y); p.y = pack_bf2(a.z, a.w);
        *(uint2*)&E[r][c4] = p;
    }
    __syncthreads();                                   // B0

    short8_t Af[4][4];
    float4_t acc[4];
    load_afrag(E, Af, m16, q);

    // ---- QKV (no internal barriers; each wave writes own cols) ----
    zero4(acc); mm_regw(Af, WqF, acc); store_rows(Qs, acc, bqv, 0, col, q);
    zero4(acc); mm_regw(Af, WkF, acc); store_rows(Ks, acc, bkv, 0, col, q);
    zero4(acc); mm_regw(Af, WvF, acc);
#pragma unroll
    for (int mt = 0; mt < 4; ++mt) {   // V transposed: Vt[col][row]
        uint2 pk;
        pk.x = pack_bf2(acc[mt][0] + bvv, acc[mt][1] + bvv);
        pk.y = pack_bf2(acc[mt][2] + bvv, acc[mt][3] + bvv);
        *(uint2*)&Vt[col][mt * 16 + q * 4] = pk;
    }
    __syncthreads();                                   // B1

    // ---- prefetch Wo, W1 frags (covers attention) ----
    short8_t WoF[4], W1aF[4], W1bF[4];
    load_wfrag(Wo, 128, col, 1.f, q, WoF);
    load_wfrag(W1, 256, col, 1.f, q, W1aF);
    load_wfrag(W1, 256, 128 + col, 1.f, q, W1bF);
    float bov = bo[col], b1a = b1[col], b1b = b1[128 + col];
    float g1v = g1[col], be1v = be1[col];

    // ---- scores, all 4 heads in one phase ----
    {
        int hd = w >> 1, ntb = (w & 1) * 2;
#pragma unroll
        for (int mt = 0; mt < 4; ++mt) {
            short8_t Aq = *(const short8_t*)&Qs[mt * 16 + m16][hd * 32 + q * 8];
#pragma unroll
            for (int nn = 0; nn < 2; ++nn) {
                int nt = ntb + nn;
                short8_t Bk = *(const short8_t*)&Ks[nt * 16 + m16][hd * 32 + q * 8];
                float4_t a = {0.f, 0.f, 0.f, 0.f};
                a = __builtin_amdgcn_mfma_f32_16x16x32_bf16(Aq, Bk, a, 0, 0, 0);
#pragma unroll
                for (int reg = 0; reg < 4; ++reg)
                    sc4[hd][mt * 16 + q * 4 + reg][nt * 16 + m16] = a[reg];
            }
        }
    }
    __syncthreads();                                   // B2

    // ---- softmax all heads; P (bf16, 1/sum folded) -> Qs/Ks ----
    {
        int pr = tid >> 1, hd2 = pr >> 6, row = pr & 63, half = (tid & 1) * 32;
        float v[32]; float mx = -1e30f;
#pragma unroll
        for (int c = 0; c < 32; ++c) { v[c] = sc4[hd2][row][half + c]; mx = fmaxf(mx, v[c]); }
        mx = fmaxf(mx, __shfl_xor(mx, 1));
        float sum = 0.f;
#pragma unroll
        for (int c = 0; c < 32; ++c) { v[c] = __expf(v[c] - mx); sum += v[c]; }
        sum += __shfl_xor(sum, 1);
        float inv = __builtin_amdgcn_rcpf(sum);
        unsigned short (*Pd)[136] = (hd2 < 2) ? Qs : Ks;
        int cb = (hd2 & 1) * 64 + half;
#pragma unroll
        for (int c = 0; c < 16; ++c)
            *(unsigned*)&Pd[row][cb + 2 * c] = pack_bf2(v[2 * c] * inv, v[2 * c + 1] * inv);
    }
    __syncthreads();                                   // B3

    // ---- PV via MFMA (K=64), O -> E ----
    {
        int hd = w >> 1, nt = w & 1;
        const unsigned short (*P)[136] = (hd < 2) ? (const unsigned short (*)[136])Qs
                                                  : (const unsigned short (*)[136])Ks;
        int pb = (hd & 1) * 64;
        int vrow = hd * 32 + nt * 16 + m16;
        short8_t B0f = *(const short8_t*)&Vt[vrow][q * 8];
        short8_t B1f = *(const short8_t*)&Vt[vrow][32 + q * 8];
#pragma unroll
        for (int mt = 0; mt < 4; ++mt) {
            short8_t A0 = *(const short8_t*)&P[mt * 16 + m16][pb + q * 8];
            short8_t A1 = *(const short8_t*)&P[mt * 16 + m16][pb + 32 + q * 8];
            float4_t a = {0.f, 0.f, 0.f, 0.f};
            a = __builtin_amdgcn_mfma_f32_16x16x32_bf16(A0, B0f, a, 0, 0, 0);
            a = __builtin_amdgcn_mfma_f32_16x16x32_bf16(A1, B1f, a, 0, 0, 0);
#pragma unroll
            for (int reg = 0; reg < 4; ++reg)
                E[mt * 16 + q * 4 + reg][vrow] = f2bf(a[reg]);
        }
    }
    __syncthreads();                                   // B4

    // ---- prefetch W2, Fk, Fv frags (covers Wo/LN1/FFN1) ----
    short8_t W2aF[4], W2bF[4], FkF[4], FvF[4];
    load_wfrag(W2, 128, col, 1.f, q, W2aF);
    load_wfrag(W2 + (size_t)128 * 128, 128, col, 1.f, q, W2bF);
    load_wfrag(Fk, 128, col, 1.f, q, FkF);
    load_wfrag(Fv, 128, col, 1.f, q, FvF);
    float b2v = b2[col], fbkv = fbk[col], fbvv = fbv[col];
    float g2v = g2[col], be2v = be2[col];

    // ---- Wo + residual(emb fp32) + LN1; h1 kept in regs ----
    load_afrag(E, Af, m16, q);
    zero4(acc); mm_regw(Af, WoF, acc);
    float h1v[4][4];
#pragma unroll
    for (int mt = 0; mt < 4; ++mt)
#pragma unroll
        for (int reg = 0; reg < 4; ++reg) {
            int row = mt * 16 + q * 4 + reg;
            h1v[mt][reg] = acc[mt][reg] + bov + embB[(size_t)row * 128 + col];
        }
#pragma unroll
    for (int mt = 0; mt < 4; ++mt)
#pragma unroll
        for (int reg = 0; reg < 4; ++reg) {
            float s = h1v[mt][reg], s2 = s * s;
            s += __shfl_xor(s, 1); s += __shfl_xor(s, 2); s += __shfl_xor(s, 4); s += __shfl_xor(s, 8);
            s2 += __shfl_xor(s2, 1); s2 += __shfl_xor(s2, 2); s2 += __shfl_xor(s2, 4); s2 += __shfl_xor(s2, 8);
            if (m16 == 0) { int row = mt * 16 + q * 4 + reg; lnp[row][w] = s; lnp2[row][w] = s2; }
        }
    __syncthreads();                                   // B5
    if (tid < 64) {
        float s = 0.f, s2 = 0.f;
#pragma unroll
        for (int k = 0; k < 8; ++k) { s += lnp[tid][k]; s2 += lnp2[tid][k]; }
        float mn = s * (1.f / 128.f);
        mean_s[tid] = mn;
        rs_s[tid] = rsqrtf(s2 * (1.f / 128.f) - mn * mn + 1e-5f);
    }
    __syncthreads();                                   // B6
#pragma unroll
    for (int mt = 0; mt < 4; ++mt)
#pragma unroll
        for (int reg = 0; reg < 4; ++reg) {
            int row = mt * 16 + q * 4 + reg;
            float hv = (h1v[mt][reg] - mean_s[row]) * rs_s[row] * g1v + be1v;
            h1v[mt][reg] = hv;
            E[row][col] = f2bf(hv);
        }
    __syncthreads();                                   // B7

    // ---- FFN1: a1 = relu(h1 @ W1 + b1) -> Qs (lo), Ks (hi) ----
    load_afrag(E, Af, m16, q);
    zero4(acc); mm_regw(Af, W1aF, acc); store_rows(Qs, acc, b1a, 1, col, q);
    zero4(acc); mm_regw(Af, W1bF, acc); store_rows(Ks, acc, b1b, 1, col, q);
    __syncthreads();                                   // B8

    // ---- FFN2 (K=256) + residual(h1 regs) + LN2 -> E (h2) ----
    {
        short8_t AfQ[4][4], AfK[4][4];
        load_afrag(Qs, AfQ, m16, q);
        load_afrag(Ks, AfK, m16, q);
        zero4(acc); mm_regw(AfQ, W2aF, acc); mm_regw(AfK, W2bF, acc);
    }
#pragma unroll
    for (int mt = 0; mt < 4; ++mt)
#pragma unroll
        for (int reg = 0; reg < 4; ++reg)
            h1v[mt][reg] = acc[mt][reg] + b2v + h1v[mt][reg];
#pragma unroll
    for (int mt = 0; mt < 4; ++mt)
#pragma unroll
        for (int reg = 0; reg < 4; ++reg) {
            float s = h1v[mt][reg], s2 = s * s;
            s += __shfl_xor(s, 1); s += __shfl_xor(s, 2); s += __shfl_xor(s, 4); s += __shfl_xor(s, 8);
            s2 += __shfl_xor(s2, 1); s2 += __shfl_xor(s2, 2); s2 += __shfl_xor(s2, 4); s2 += __shfl_xor(s2, 8);
            if (m16 == 0) { int row = mt * 16 + q * 4 + reg; lnp[row][w] = s; lnp2[row][w] = s2; }
        }
    __syncthreads();                                   // B9
    if (tid < 64) {
        float s = 0.f, s2 = 0.f;
#pragma unroll
        for (int k = 0; k < 8; ++k) { s += lnp[tid][k]; s2 += lnp2[tid][k]; }
        float mn = s * (1.f / 128.f);
        mean_s[tid] = mn;
        rs_s[tid] = rsqrtf(s2 * (1.f / 128.f) - mn * mn + 1e-5f);
    }
    __syncthreads();                                   // B10
#pragma unroll
    for (int mt = 0; mt < 4; ++mt)
#pragma unroll
        for (int reg = 0; reg < 4; ++reg) {
            int row = mt * 16 + q * 4 + reg;
            float hv = (h1v[mt][reg] - mean_s[row]) * rs_s[row] * g2v + be2v;
            E[row][col] = f2bf(hv);   // h2
        }
    __syncthreads();                                   // B11

    // ---- final projections: fk -> Qs, fv -> Ks; fq via VALU ----
    load_afrag(E, Af, m16, q);
    zero4(acc); mm_regw(Af, FkF, acc); store_rows(Qs, acc, fbkv, 0, col, q);
    zero4(acc); mm_regw(Af, FvF, acc); store_rows(Ks, acc, fbvv, 0, col, q);
    if (tid < 128) {
        fo_s[tid] = Fout[tid];
        float a = fbq[tid];
        for (int mm2 = 0; mm2 < 128; ++mm2)
            a = fmaf(bf2f(E[63][mm2]), Fq[mm2 * 128 + tid], a);
        fq_s[tid] = a;
    }
    __syncthreads();                                   // B12

    {   // e[dd] = tanh(fq + fk[dd]) . Fout + fbout
        int dd = tid >> 3, c8 = tid & 7;
        float p = 0.f;
#pragma unroll
        for (int c = 0; c < 16; ++c) {
            int cc = c8 * 16 + c;
            float t = fq_s[cc] + bf2f(Qs[dd][cc]);
            float tn = 1.f - 2.f * __builtin_amdgcn_rcpf(
                __builtin_amdgcn_exp2f(2.f * LOG2E * t) + 1.f);
            p = fmaf(tn, fo_s[cc], p);
        }
        p += __shfl_xor(p, 1); p += __shfl_xor(p, 2); p += __shfl_xor(p, 4);
        if (c8 == 0) e_s[dd] = p + fbout[0];
    }
    __syncthreads();                                   // B13
    if (tid < 64) {
        float e = e_s[tid], mx = e;
        for (int o = 32; o; o >>= 1) mx = fmaxf(mx, __shfl_xor(mx, o));
        float pe = __expf(e - mx);
        float s = pe;
        for (int o = 32; o; o >>= 1) s += __shfl_xor(s, o);
        e_s[tid] = pe / s;
    }
    __syncthreads();                                   // B14
    if (tid < 256) {
        int c2 = tid & 127, rg2 = tid >> 7;
        float a = 0.f;
        for (int d2 = rg2 * 32; d2 < rg2 * 32 + 32; ++d2)
            a = fmaf(e_s[d2], bf2f(Ks[d2][c2]), a);
        red_s[tid] = a;
    }
    __syncthreads();                                   // B15
    if (tid < 128)
        out[(size_t)b * 128 + tid] = red_s[tid] + red_s[tid + 128];
}

// ---------------- launch ---------------------------------------------------
extern "C" void kernel_launch(void* const* d_in, const int* in_sizes, int n_in,
                              void* d_out, int out_size, void* d_ws, size_t ws_size,
                              hipStream_t stream)
{
    const float* x    = (const float*)d_in[0];
    const int*   mask = (const int*)d_in[1];
    const float* Wih  = (const float*)d_in[2];
    const float* Whh  = (const float*)d_in[3];
    const float* bih  = (const float*)d_in[4];
    const float* bhh  = (const float*)d_in[5];
    const float* Wq = (const float*)d_in[6];   const float* bq = (const float*)d_in[7];
    const float* Wk = (const float*)d_in[8];   const float* bk = (const float*)d_in[9];
    const float* Wv = (const float*)d_in[10];  const float* bv = (const float*)d_in[11];
    const float* Wo = (const float*)d_in[12];  const float* bo = (const float*)d_in[13];
    const float* W1 = (const float*)d_in[14];  const float* b1 = (const float*)d_in[15];
    const float* W2 = (const float*)d_in[16];  const float* b2 = (const float*)d_in[17];
    const float* g1 = (const float*)d_in[18];  const float* be1 = (const float*)d_in[19];
    const float* g2 = (const float*)d_in[20];  const float* be2 = (const float*)d_in[21];
    const float* Fq = (const float*)d_in[22];  const float* fbq = (const float*)d_in[23];
    const float* Fk = (const float*)d_in[24];  const float* fbk = (const float*)d_in[25];
    const float* Fv = (const float*)d_in[26];  const float* fbv = (const float*)d_in[27];
    const float* Fout = (const float*)d_in[28]; const float* fbout = (const float*)d_in[29];
    float* out = (float*)d_out;
    float* ws  = (float*)d_ws;

    float* emb = ws;   // 1048576 floats

    gru_mfma_kernel<<<dim3(DD, BB / 16), 512, 0, stream>>>(x, mask, Wih, Whh, bih, bhh, emb);
    tail_kernel<<<BB, 512, 0, stream>>>(
        emb, Wq, bq, Wk, bk, Wv, bv, Wo, bo, W1, b1, W2, b2,
        g1, be1, g2, be2, Fq, fbq, Fk, fbk, Fv, fbv, Fout, fbout, out);
}